// Round 4
// baseline (391.671 us; speedup 1.0000x reference)
//
#include <hip/hip_runtime.h>

typedef unsigned short u16;
typedef __attribute__((ext_vector_type(4))) int v4i;
typedef __attribute__((ext_vector_type(4))) float f32x4;
typedef __attribute__((ext_vector_type(4))) u16 v4u;
typedef __attribute__((ext_vector_type(8))) __bf16 bf16x8;

#define B_ 4
#define T_ 2048
#define C_ 1024
#define H_ 16
#define HD_ 64
#define C3_ 3072

__device__ __forceinline__ u16 f2b(float f) {
    unsigned u = __builtin_bit_cast(unsigned, f);
    u += 0x7FFFu + ((u >> 16) & 1u);
    return (u16)(u >> 16);
}
__device__ __forceinline__ float b2f(u16 h) {
    unsigned u = ((unsigned)h) << 16;
    return __builtin_bit_cast(float, u);
}

// ---------------- cast f32 -> bf16 ----------------
__global__ __launch_bounds__(256) void cast_f32_bf16(const float* __restrict__ in,
                                                     u16* __restrict__ out, int n4) {
    int i = blockIdx.x * 256 + threadIdx.x;
    if (i >= n4) return;
    f32x4 v = *(const f32x4*)(in + (size_t)i * 4);
    v4u o;
    o[0] = f2b(v[0]); o[1] = f2b(v[1]); o[2] = f2b(v[2]); o[3] = f2b(v[3]);
    *(v4u*)(out + (size_t)i * 4) = o;
}

// ---------------- rope table: [t][j] -> (cos, sin) bf16, j<32 ----------------
__global__ __launch_bounds__(256) void rope_tab(u16* __restrict__ rope) {
    int id = blockIdx.x * 256 + threadIdx.x;   // T_*32 entries
    int t = id >> 5, j = id & 31;
    float invf = exp2f(-(float)j * (13.287712379549449f / 32.0f));  // 10000^(-j/32)
    float fr = (float)t * invf;
    float s, c;
    sincosf(fr, &s, &c);
    rope[id * 2]     = f2b(c);
    rope[id * 2 + 1] = f2b(s);
}

// ---------------- GEMM: out[m][n] = sum_k A[m][k]*Bmat[n][k] ----------------
__device__ __forceinline__ void store_out(u16* p, float v)   { *p = f2b(v); }
__device__ __forceinline__ void store_out(float* p, float v) { *p = v; }

template <typename OutT>
__global__ __launch_bounds__(256) void gemm_bt(const u16* __restrict__ A, const u16* __restrict__ Bm,
                                               OutT* __restrict__ Cout, int Mdim, int Ndim, int Kdim) {
    __shared__ u16 As[128][40];
    __shared__ u16 Bs[128][40];
    const int tid = threadIdx.x;
    const int row0 = blockIdx.y * 128;
    const int col0 = blockIdx.x * 128;
    const int w = tid >> 6, lane = tid & 63;
    const int wm = w >> 1, wn = w & 1;
    const int lr = lane & 15, lk = lane >> 4;

    const f32x4 zf = {0.f, 0.f, 0.f, 0.f};
    f32x4 acc[4][4];
#pragma unroll
    for (int m = 0; m < 4; m++)
#pragma unroll
        for (int n = 0; n < 4; n++) acc[m][n] = zf;

    const u16* Ab = A + (size_t)row0 * Kdim;
    const u16* Bb = Bm + (size_t)col0 * Kdim;
    const int r0 = tid >> 2, q0 = tid & 3;
    const int r1 = r0 + 64;

    for (int k0 = 0; k0 < Kdim; k0 += 32) {
        *(v4i*)&As[r0][q0 * 8] = *(const v4i*)(Ab + (size_t)r0 * Kdim + k0 + q0 * 8);
        *(v4i*)&Bs[r0][q0 * 8] = *(const v4i*)(Bb + (size_t)r0 * Kdim + k0 + q0 * 8);
        *(v4i*)&As[r1][q0 * 8] = *(const v4i*)(Ab + (size_t)r1 * Kdim + k0 + q0 * 8);
        *(v4i*)&Bs[r1][q0 * 8] = *(const v4i*)(Bb + (size_t)r1 * Kdim + k0 + q0 * 8);
        __syncthreads();
        bf16x8 af[4], bfr[4];
#pragma unroll
        for (int m = 0; m < 4; m++) af[m]  = *(const bf16x8*)&As[wm * 64 + m * 16 + lr][lk * 8];
#pragma unroll
        for (int n = 0; n < 4; n++) bfr[n] = *(const bf16x8*)&Bs[wn * 64 + n * 16 + lr][lk * 8];
#pragma unroll
        for (int m = 0; m < 4; m++)
#pragma unroll
            for (int n = 0; n < 4; n++)
                acc[m][n] = __builtin_amdgcn_mfma_f32_16x16x32_bf16(af[m], bfr[n], acc[m][n], 0, 0, 0);
        __syncthreads();
    }
#pragma unroll
    for (int m = 0; m < 4; m++)
#pragma unroll
        for (int n = 0; n < 4; n++) {
            const int rr = row0 + wm * 64 + m * 16 + lk * 4;
            const int cc = col0 + wn * 64 + n * 16 + lr;
#pragma unroll
            for (int j = 0; j < 4; j++)
                store_out(Cout + (size_t)(rr + j) * Ndim + cc, acc[m][n][j]);
        }
}

// ---------------- RMSNorm + RoPE for q,k; transpose v -> [bh][d][t] ----------
__global__ __launch_bounds__(256) void norm_rope(const u16* __restrict__ qkv, u16* __restrict__ Qn,
                                                 u16* __restrict__ Kn, u16* __restrict__ Vt,
                                                 const u16* __restrict__ rope) {
    __shared__ u16 sl[3][64][72];
    const int tid = threadIdx.x, bid = blockIdx.x;
    const int tt = bid & 31, bh = bid >> 5;
    const int b = bh >> 4, h = bh & 15;
    const int t0 = tt * 64;
    const size_t base = ((size_t)(b * T_) + t0) * C3_ + h * HD_;
#pragma unroll
    for (int i = 0; i < 6; i++) {
        int c = tid + i * 256;            // 1536 16B chunks
        int p = c >> 9, rc = c & 511;
        int r = rc >> 3, ch = rc & 7;
        *(v4i*)&sl[p][r][ch * 8] = *(const v4i*)(qkv + base + (size_t)r * C3_ + p * C_ + ch * 8);
    }
    __syncthreads();
    const int row = tid >> 2, q4 = tid & 3;  // 4 lanes per row
    const u16* rp = rope + (size_t)(t0 + row) * 64;
#pragma unroll
    for (int p = 0; p < 2; p++) {            // p=0: q, p=1: k
        float ss = 0.f;
#pragma unroll
        for (int j = 0; j < 16; j++) { float v = b2f(sl[p][row][q4 * 16 + j]); ss += v * v; }
        ss += __shfl_xor(ss, 1, 64);
        ss += __shfl_xor(ss, 2, 64);
        const float rms = rsqrtf(ss * (1.f / 64.f) + 1.1920929e-7f);
        u16* outp = (p == 0 ? Qn : Kn) + ((size_t)bh * T_ + t0 + row) * HD_;
#pragma unroll
        for (int j = 0; j < 16; j++) {
            int d = q4 * 16 + j;
            float y;
            if (d < 32) {
                float x1 = b2f(sl[p][row][d]) * rms;
                float x2 = b2f(sl[p][row][d + 32]) * rms;
                y = x1 * b2f(rp[d * 2]) + x2 * b2f(rp[d * 2 + 1]);      // x1*cos + x2*sin
            } else {
                int dd = d - 32;
                float x1 = b2f(sl[p][row][dd]) * rms;
                float x2 = b2f(sl[p][row][d]) * rms;
                y = x2 * b2f(rp[dd * 2]) - x1 * b2f(rp[dd * 2 + 1]);    // FIXED: x2*cos - x1*sin
            }
            outp[d] = f2b(y);
        }
    }
    const int d = tid >> 2, tq = tid & 3;
    u16* vout = Vt + ((size_t)bh * HD_ + d) * T_ + t0 + tq * 16;
#pragma unroll
    for (int jj = 0; jj < 4; jj++) {
        v4u pk;
#pragma unroll
        for (int j2 = 0; j2 < 4; j2++) pk[j2] = sl[2][tq * 16 + jj * 4 + j2][d];
        *(v4u*)(vout + jj * 4) = pk;
    }
}

// ---------------- causal flash attention (4 waves, 16 q-rows each) ----------
__global__ __launch_bounds__(256) void attn_fwd(const u16* __restrict__ Qn, const u16* __restrict__ Kn,
                                                const u16* __restrict__ Vt, u16* __restrict__ Y) {
    __shared__ u16 Ks[64][72];
    __shared__ u16 Vs[64][72];          // V^T tile: [d][key]
    __shared__ u16 Ps[4][16][72];       // per-wave P tile [q][key]
    const int tid = threadIdx.x, bid = blockIdx.x;
    const int qt = bid & 31, bh = bid >> 5;
    const int b = bh >> 4, h = bh & 15;
    const int w = tid >> 6, lane = tid & 63, lr = lane & 15, lk = lane >> 4;
    const u16* Qp = Qn + (size_t)bh * T_ * HD_;
    const u16* Kp = Kn + (size_t)bh * T_ * HD_;
    const u16* Vp = Vt + (size_t)bh * HD_ * T_;
    const int q0w = qt * 64 + w * 16;
    const bf16x8 qf0 = *(const bf16x8*)(Qp + (size_t)(q0w + lr) * HD_ + lk * 8);
    const bf16x8 qf1 = *(const bf16x8*)(Qp + (size_t)(q0w + lr) * HD_ + 32 + lk * 8);
    const f32x4 zf = {0.f, 0.f, 0.f, 0.f};
    f32x4 O[4]; O[0] = zf; O[1] = zf; O[2] = zf; O[3] = zf;
    f32x4 mrow = {-1e30f, -1e30f, -1e30f, -1e30f};
    f32x4 lrow = zf;
    const float SC = 0.125f * 1.44269504088896341f;   // scale * log2(e)
    const int sr = tid >> 3, sc8 = tid & 7;
    const int ntile = qt + 1;
    for (int kt = 0; kt < ntile; kt++) {
        const int kv0 = kt * 64;
        __syncthreads();
        *(v4i*)&Ks[sr][sc8 * 8]      = *(const v4i*)(Kp + (size_t)(kv0 + sr) * HD_ + sc8 * 8);
        *(v4i*)&Ks[sr + 32][sc8 * 8] = *(const v4i*)(Kp + (size_t)(kv0 + sr + 32) * HD_ + sc8 * 8);
        *(v4i*)&Vs[sr][sc8 * 8]      = *(const v4i*)(Vp + (size_t)sr * T_ + kv0 + sc8 * 8);
        *(v4i*)&Vs[sr + 32][sc8 * 8] = *(const v4i*)(Vp + (size_t)(sr + 32) * T_ + kv0 + sc8 * 8);
        __syncthreads();
        // S tile: lane holds S[q = lk*4+j][key = ct*16+lr]
        f32x4 s[4];
#pragma unroll
        for (int ct = 0; ct < 4; ct++) {
            bf16x8 kf0 = *(const bf16x8*)&Ks[ct * 16 + lr][lk * 8];
            bf16x8 kf1 = *(const bf16x8*)&Ks[ct * 16 + lr][32 + lk * 8];
            s[ct] = __builtin_amdgcn_mfma_f32_16x16x32_bf16(qf0, kf0, zf, 0, 0, 0);
            s[ct] = __builtin_amdgcn_mfma_f32_16x16x32_bf16(qf1, kf1, s[ct], 0, 0, 0);
        }
        if (kt == qt) {
#pragma unroll
            for (int ct = 0; ct < 4; ct++) {
                const int key = kv0 + ct * 16 + lr;
#pragma unroll
                for (int j = 0; j < 4; j++)
                    if (key > q0w + lk * 4 + j) s[ct][j] = -1e30f;
            }
        }
        f32x4 mx;
#pragma unroll
        for (int j = 0; j < 4; j++)
            mx[j] = fmaxf(fmaxf(s[0][j], s[1][j]), fmaxf(s[2][j], s[3][j]));
#pragma unroll
        for (int off = 1; off < 16; off <<= 1)
#pragma unroll
            for (int j = 0; j < 4; j++)
                mx[j] = fmaxf(mx[j], __shfl_xor(mx[j], off, 64));
        f32x4 alpha;
#pragma unroll
        for (int j = 0; j < 4; j++) {
            const float mn = fmaxf(mrow[j], mx[j]);
            alpha[j] = exp2f((mrow[j] - mn) * SC);
            mrow[j] = mn;
        }
#pragma unroll
        for (int j = 0; j < 4; j++) lrow[j] *= alpha[j];
#pragma unroll
        for (int dt = 0; dt < 4; dt++)
#pragma unroll
            for (int j = 0; j < 4; j++) O[dt][j] *= alpha[j];
#pragma unroll
        for (int ct = 0; ct < 4; ct++)
#pragma unroll
            for (int j = 0; j < 4; j++) {
                const float p = exp2f((s[ct][j] - mrow[j]) * SC);
                lrow[j] += p;
                Ps[w][lk * 4 + j][ct * 16 + lr] = f2b(p);
            }
        // wave-local LDS RAW: DS ops are in-order per wave; compiler inserts lgkmcnt
        const bf16x8 pa0 = *(const bf16x8*)&Ps[w][lr][lk * 8];
        const bf16x8 pa1 = *(const bf16x8*)&Ps[w][lr][32 + lk * 8];
#pragma unroll
        for (int dt = 0; dt < 4; dt++) {
            bf16x8 v0 = *(const bf16x8*)&Vs[dt * 16 + lr][lk * 8];
            bf16x8 v1 = *(const bf16x8*)&Vs[dt * 16 + lr][32 + lk * 8];
            O[dt] = __builtin_amdgcn_mfma_f32_16x16x32_bf16(pa0, v0, O[dt], 0, 0, 0);
            O[dt] = __builtin_amdgcn_mfma_f32_16x16x32_bf16(pa1, v1, O[dt], 0, 0, 0);
        }
    }
#pragma unroll
    for (int off = 1; off < 16; off <<= 1)
#pragma unroll
        for (int j = 0; j < 4; j++) lrow[j] += __shfl_xor(lrow[j], off, 64);
    f32x4 inv;
#pragma unroll
    for (int j = 0; j < 4; j++) inv[j] = 1.0f / lrow[j];
#pragma unroll
    for (int dt = 0; dt < 4; dt++)
#pragma unroll
        for (int j = 0; j < 4; j++) {
            const int t = q0w + lk * 4 + j;
            const int d = dt * 16 + lr;
            Y[((size_t)(b * T_) + t) * C_ + h * HD_ + d] = f2b(O[dt][j] * inv[j]);
        }
}

extern "C" void kernel_launch(void* const* d_in, const int* in_sizes, int n_in,
                              void* d_out, int out_size, void* d_ws, size_t ws_size,
                              hipStream_t stream) {
    const float* x      = (const float*)d_in[0];
    const float* w_attn = (const float*)d_in[1];
    const float* w_proj = (const float*)d_in[2];
    float* out = (float*)d_out;
    char* ws = (char*)d_ws;
    // lifetime-overlapped workspace, peak 109,314,048 B (~104.3 MB)
    u16* Wpb = (u16*)(ws + 0);              // 2 MB,   live: all
    u16* Rp  = (u16*)(ws + 2097152);        // 256 KB, live: -> norm
    u16* Xb  = (u16*)(ws + 2359296);        // 16 MB,  live: -> gemm1
    u16* Wab = (u16*)(ws + 19136512);       // 6 MB,   live: -> gemm1
    u16* QKV = (u16*)(ws + 25427968);       // 48 MB,  live: gemm1 -> norm
    u16* Qn  = (u16*)(ws + 2359296);        // 16 MB,  over Xb (dead), norm -> attn
    u16* Kn  = (u16*)(ws + 75759616);       // 16 MB,  norm -> attn
    u16* Vt  = (u16*)(ws + 92536832);       // 16 MB,  norm -> attn  [bh][d][t]
    u16* Yb  = (u16*)(ws + 25427968);       // 16 MB,  over QKV (dead), attn -> gemm2

    cast_f32_bf16<<<8192, 256, 0, stream>>>(x, Xb, 2097152);
    cast_f32_bf16<<<3072, 256, 0, stream>>>(w_attn, Wab, 786432);
    cast_f32_bf16<<<1024, 256, 0, stream>>>(w_proj, Wpb, 262144);
    rope_tab<<<256, 256, 0, stream>>>(Rp);
    gemm_bt<u16><<<dim3(24, 64), 256, 0, stream>>>(Xb, Wab, QKV, 8192, 3072, 1024);
    norm_rope<<<2048, 256, 0, stream>>>(QKV, Qn, Kn, Vt, Rp);
    attn_fwd<<<2048, 256, 0, stream>>>(Qn, Kn, Vt, Yb);
    gemm_bt<float><<<dim3(8, 64), 256, 0, stream>>>(Yb, Wpb, out, 8192, 1024, 1024);
}

// Round 5
// 325.805 us; speedup vs baseline: 1.2022x; 1.2022x over previous
//
#include <hip/hip_runtime.h>

typedef unsigned short u16;
typedef unsigned int u32;
typedef __attribute__((ext_vector_type(4))) int v4i;
typedef __attribute__((ext_vector_type(4))) float f32x4;
typedef __attribute__((ext_vector_type(16))) float f32x16;
typedef __attribute__((ext_vector_type(4))) u16 v4u;
typedef __attribute__((ext_vector_type(2))) u32 u32x2;
typedef __attribute__((ext_vector_type(8))) __bf16 bf16x8;

#define B_ 4
#define T_ 2048
#define C_ 1024
#define H_ 16
#define HD_ 64
#define C3_ 3072

__device__ __forceinline__ u16 f2b(float f) {
    unsigned u = __builtin_bit_cast(unsigned, f);
    u += 0x7FFFu + ((u >> 16) & 1u);
    return (u16)(u >> 16);
}
__device__ __forceinline__ float b2f(u16 h) {
    unsigned u = ((unsigned)h) << 16;
    return __builtin_bit_cast(float, u);
}
__device__ __forceinline__ u32 pkbf(float lo, float hi) {
    return (u32)f2b(lo) | ((u32)f2b(hi) << 16);
}

// ---------------- cast f32 -> bf16 ----------------
__global__ __launch_bounds__(256) void cast_f32_bf16(const float* __restrict__ in,
                                                     u16* __restrict__ out, int n4) {
    int i = blockIdx.x * 256 + threadIdx.x;
    if (i >= n4) return;
    f32x4 v = *(const f32x4*)(in + (size_t)i * 4);
    v4u o;
    o[0] = f2b(v[0]); o[1] = f2b(v[1]); o[2] = f2b(v[2]); o[3] = f2b(v[3]);
    *(v4u*)(out + (size_t)i * 4) = o;
}

// ---------------- rope table ----------------
__global__ __launch_bounds__(256) void rope_tab(u16* __restrict__ rope) {
    int id = blockIdx.x * 256 + threadIdx.x;   // T_*32 entries
    int t = id >> 5, j = id & 31;
    float invf = exp2f(-(float)j * (13.287712379549449f / 32.0f));  // 10000^(-j/32)
    float fr = (float)t * invf;
    float s, c;
    sincosf(fr, &s, &c);
    rope[id * 2]     = f2b(c);
    rope[id * 2 + 1] = f2b(s);
}

// ---------------- GEMM: out[m][n] = sum_k A[m][k]*Bmat[n][k] ----------------
__device__ __forceinline__ void store_out(u16* p, float v)   { *p = f2b(v); }
__device__ __forceinline__ void store_out(float* p, float v) { *p = v; }

template <typename OutT>
__global__ __launch_bounds__(256) void gemm_bt(const u16* __restrict__ A, const u16* __restrict__ Bm,
                                               OutT* __restrict__ Cout, int Mdim, int Ndim, int Kdim) {
    __shared__ u16 As[128][40];
    __shared__ u16 Bs[128][40];
    const int tid = threadIdx.x;
    const int row0 = blockIdx.y * 128;
    const int col0 = blockIdx.x * 128;
    const int w = tid >> 6, lane = tid & 63;
    const int wm = w >> 1, wn = w & 1;
    const int lr = lane & 15, lk = lane >> 4;

    const f32x4 zf = {0.f, 0.f, 0.f, 0.f};
    f32x4 acc[4][4];
#pragma unroll
    for (int m = 0; m < 4; m++)
#pragma unroll
        for (int n = 0; n < 4; n++) acc[m][n] = zf;

    const u16* Ab = A + (size_t)row0 * Kdim;
    const u16* Bb = Bm + (size_t)col0 * Kdim;
    const int r0 = tid >> 2, q0 = tid & 3;
    const int r1 = r0 + 64;

    for (int k0 = 0; k0 < Kdim; k0 += 32) {
        *(v4i*)&As[r0][q0 * 8] = *(const v4i*)(Ab + (size_t)r0 * Kdim + k0 + q0 * 8);
        *(v4i*)&Bs[r0][q0 * 8] = *(const v4i*)(Bb + (size_t)r0 * Kdim + k0 + q0 * 8);
        *(v4i*)&As[r1][q0 * 8] = *(const v4i*)(Ab + (size_t)r1 * Kdim + k0 + q0 * 8);
        *(v4i*)&Bs[r1][q0 * 8] = *(const v4i*)(Bb + (size_t)r1 * Kdim + k0 + q0 * 8);
        __syncthreads();
        bf16x8 af[4], bfr[4];
#pragma unroll
        for (int m = 0; m < 4; m++) af[m]  = *(const bf16x8*)&As[wm * 64 + m * 16 + lr][lk * 8];
#pragma unroll
        for (int n = 0; n < 4; n++) bfr[n] = *(const bf16x8*)&Bs[wn * 64 + n * 16 + lr][lk * 8];
#pragma unroll
        for (int m = 0; m < 4; m++)
#pragma unroll
            for (int n = 0; n < 4; n++)
                acc[m][n] = __builtin_amdgcn_mfma_f32_16x16x32_bf16(af[m], bfr[n], acc[m][n], 0, 0, 0);
        __syncthreads();
    }
#pragma unroll
    for (int m = 0; m < 4; m++)
#pragma unroll
        for (int n = 0; n < 4; n++) {
            const int rr = row0 + wm * 64 + m * 16 + lk * 4;
            const int cc = col0 + wn * 64 + n * 16 + lr;
#pragma unroll
            for (int j = 0; j < 4; j++)
                store_out(Cout + (size_t)(rr + j) * Ndim + cc, acc[m][n][j]);
        }
}

// ---------------- RMSNorm + RoPE for q,k; transpose v -> [bh][d][t] ----------
__global__ __launch_bounds__(256) void norm_rope(const u16* __restrict__ qkv, u16* __restrict__ Qn,
                                                 u16* __restrict__ Kn, u16* __restrict__ Vt,
                                                 const u16* __restrict__ rope) {
    __shared__ u16 sl[3][64][72];
    const int tid = threadIdx.x, bid = blockIdx.x;
    const int tt = bid & 31, bh = bid >> 5;
    const int b = bh >> 4, h = bh & 15;
    const int t0 = tt * 64;
    const size_t base = ((size_t)(b * T_) + t0) * C3_ + h * HD_;
#pragma unroll
    for (int i = 0; i < 6; i++) {
        int c = tid + i * 256;            // 1536 16B chunks
        int p = c >> 9, rc = c & 511;
        int r = rc >> 3, ch = rc & 7;
        *(v4i*)&sl[p][r][ch * 8] = *(const v4i*)(qkv + base + (size_t)r * C3_ + p * C_ + ch * 8);
    }
    __syncthreads();
    const int row = tid >> 2, q4 = tid & 3;  // 4 lanes per row
    const u16* rp = rope + (size_t)(t0 + row) * 64;
#pragma unroll
    for (int p = 0; p < 2; p++) {            // p=0: q, p=1: k
        float ss = 0.f;
#pragma unroll
        for (int j = 0; j < 16; j++) { float v = b2f(sl[p][row][q4 * 16 + j]); ss += v * v; }
        ss += __shfl_xor(ss, 1, 64);
        ss += __shfl_xor(ss, 2, 64);
        const float rms = rsqrtf(ss * (1.f / 64.f) + 1.1920929e-7f);
        u16* outp = (p == 0 ? Qn : Kn) + ((size_t)bh * T_ + t0 + row) * HD_;
#pragma unroll
        for (int j = 0; j < 16; j++) {
            int d = q4 * 16 + j;
            float y;
            if (d < 32) {
                float x1 = b2f(sl[p][row][d]) * rms;
                float x2 = b2f(sl[p][row][d + 32]) * rms;
                y = x1 * b2f(rp[d * 2]) + x2 * b2f(rp[d * 2 + 1]);      // x1*cos + x2*sin
            } else {
                int dd = d - 32;
                float x1 = b2f(sl[p][row][dd]) * rms;
                float x2 = b2f(sl[p][row][d]) * rms;
                y = x2 * b2f(rp[dd * 2]) - x1 * b2f(rp[dd * 2 + 1]);    // x2*cos - x1*sin
            }
            outp[d] = f2b(y);
        }
    }
    const int d = tid >> 2, tq = tid & 3;
    u16* vout = Vt + ((size_t)bh * HD_ + d) * T_ + t0 + tq * 16;
#pragma unroll
    for (int jj = 0; jj < 4; jj++) {
        v4u pk;
#pragma unroll
        for (int j2 = 0; j2 < 4; j2++) pk[j2] = sl[2][tq * 16 + jj * 4 + j2][d];
        *(v4u*)(vout + jj * 4) = pk;
    }
}

// ---------------- causal flash attention v2: 32x32 swapped-QK^T, no LDS -----
// grid 512: gid = blk*64 + bh  (same-bh blocks land on one XCD: gid%8 = bh%8)
// warp wi = blk*4 + w processes q-tiles {63-wi, wi}  (perfect balance)
__global__ __launch_bounds__(256) void attn_fwd2(const u16* __restrict__ Qn, const u16* __restrict__ Kn,
                                                 const u16* __restrict__ Vt, u16* __restrict__ Yb) {
    const int tid = threadIdx.x;
    const int w = tid >> 6, lane = tid & 63, la = lane & 31, hi = lane >> 5;
    const int gid = blockIdx.x;
    const int bh = gid & 63, blk = gid >> 6;
    const int b = bh >> 4, h = bh & 15;
    const int wi = blk * 4 + w;
    const u16* Qp = Qn + (size_t)bh * T_ * HD_;
    const u16* Kp = Kn + (size_t)bh * T_ * HD_;
    const u16* Vp = Vt + (size_t)bh * HD_ * T_;
    const float SC = 0.125f * 1.44269504088896341f;

    for (int hh = 0; hh < 2; hh++) {
        const int qt = hh ? wi : 63 - wi;
        const int q0 = qt * 32;
        const int q = q0 + la;
        bf16x8 qf[4];
#pragma unroll
        for (int c = 0; c < 4; c++)
            qf[c] = *(const bf16x8*)(Qp + (size_t)q * HD_ + c * 16 + hi * 8);
        f32x16 O0, O1;
#pragma unroll
        for (int r = 0; r < 16; r++) { O0[r] = 0.f; O1[r] = 0.f; }
        float m = -3e38f, l = 0.f;
        const int ntile = (q0 + 31) / 64 + 1;
        for (int kt = 0; kt < ntile; kt++) {
            const int kv0 = kt * 64;
            f32x16 s0, s1;
#pragma unroll
            for (int r = 0; r < 16; r++) { s0[r] = 0.f; s1[r] = 0.f; }
#pragma unroll
            for (int c = 0; c < 4; c++) {
                bf16x8 kf0 = *(const bf16x8*)(Kp + (size_t)(kv0 + la) * HD_ + c * 16 + hi * 8);
                bf16x8 kf1 = *(const bf16x8*)(Kp + (size_t)(kv0 + 32 + la) * HD_ + c * 16 + hi * 8);
                s0 = __builtin_amdgcn_mfma_f32_32x32x16_bf16(kf0, qf[c], s0, 0, 0, 0);
                s1 = __builtin_amdgcn_mfma_f32_32x32x16_bf16(kf1, qf[c], s1, 0, 0, 0);
            }
            if (kt == ntile - 1) {
#pragma unroll
                for (int r = 0; r < 16; r++) {
                    const int cr = (r & 3) + 8 * (r >> 2) + 4 * hi;
                    if (kv0 + cr > q)      s0[r] = -3e38f;
                    if (kv0 + 32 + cr > q) s1[r] = -3e38f;
                }
            }
            float mx = fmaxf(s0[0], s1[0]);
#pragma unroll
            for (int r = 1; r < 16; r++) mx = fmaxf(mx, fmaxf(s0[r], s1[r]));
            mx = fmaxf(mx, __shfl_xor(mx, 32, 64));
            // T13 defer-max: only rescale when the running max grows materially
            if (__ballot(mx > m + 16.6355324f)) {   // 3.0/SC
                const float mn = fmaxf(m, mx);
                const float al = exp2f((m - mn) * SC);
                m = mn;
                l *= al;
                O0 *= al;
                O1 *= al;
            }
            float p0[16], p1[16];
            float ps = 0.f;
#pragma unroll
            for (int r = 0; r < 16; r++) {
                p0[r] = exp2f((s0[r] - m) * SC);
                p1[r] = exp2f((s1[r] - m) * SC);
                ps += p0[r] + p1[r];
            }
            ps += __shfl_xor(ps, 32, 64);
            l += ps;
#pragma unroll
            for (int g = 0; g < 2; g++) {
                u32 P2[8], sh[8];
#pragma unroll
                for (int j = 0; j < 8; j++)
                    P2[j] = g ? pkbf(p1[2 * j], p1[2 * j + 1]) : pkbf(p0[2 * j], p0[2 * j + 1]);
#pragma unroll
                for (int j = 0; j < 8; j++) sh[j] = (u32)__shfl_xor((int)P2[j], 32, 64);
                v4i w0, w1;
                if (hi == 0) {
                    w0[0] = P2[0]; w0[1] = P2[1]; w0[2] = sh[0]; w0[3] = sh[1];
                    w1[0] = P2[4]; w1[1] = P2[5]; w1[2] = sh[4]; w1[3] = sh[5];
                } else {
                    w0[0] = sh[2]; w0[1] = sh[3]; w0[2] = P2[2]; w0[3] = P2[3];
                    w1[0] = sh[6]; w1[1] = sh[7]; w1[2] = P2[6]; w1[3] = P2[7];
                }
                const bf16x8 pa0 = __builtin_bit_cast(bf16x8, w0);
                const bf16x8 pa1 = __builtin_bit_cast(bf16x8, w1);
                const u16* vbase = Vp + kv0 + g * 32;
#pragma unroll
                for (int ks = 0; ks < 2; ks++) {
                    const bf16x8 pa = ks ? pa1 : pa0;
                    bf16x8 vf0 = *(const bf16x8*)(vbase + (size_t)la * T_ + ks * 16 + hi * 8);
                    bf16x8 vf1 = *(const bf16x8*)(vbase + (size_t)(32 + la) * T_ + ks * 16 + hi * 8);
                    O0 = __builtin_amdgcn_mfma_f32_32x32x16_bf16(vf0, pa, O0, 0, 0, 0);
                    O1 = __builtin_amdgcn_mfma_f32_32x32x16_bf16(vf1, pa, O1, 0, 0, 0);
                }
            }
        }
        const float inv = 1.f / l;
        u16* yrow = Yb + ((size_t)(b * T_) + q) * C_ + h * HD_;
#pragma unroll
        for (int r4 = 0; r4 < 4; r4++) {
            u32x2 st0, st1;
            st0[0] = pkbf(O0[r4 * 4 + 0] * inv, O0[r4 * 4 + 1] * inv);
            st0[1] = pkbf(O0[r4 * 4 + 2] * inv, O0[r4 * 4 + 3] * inv);
            st1[0] = pkbf(O1[r4 * 4 + 0] * inv, O1[r4 * 4 + 1] * inv);
            st1[1] = pkbf(O1[r4 * 4 + 2] * inv, O1[r4 * 4 + 3] * inv);
            *(u32x2*)(yrow + r4 * 8 + hi * 4)      = st0;
            *(u32x2*)(yrow + 32 + r4 * 8 + hi * 4) = st1;
        }
    }
}

extern "C" void kernel_launch(void* const* d_in, const int* in_sizes, int n_in,
                              void* d_out, int out_size, void* d_ws, size_t ws_size,
                              hipStream_t stream) {
    const float* x      = (const float*)d_in[0];
    const float* w_attn = (const float*)d_in[1];
    const float* w_proj = (const float*)d_in[2];
    float* out = (float*)d_out;
    char* ws = (char*)d_ws;
    // lifetime-overlapped workspace, peak ~104.3 MB
    u16* Wpb = (u16*)(ws + 0);              // 2 MB,   live: all
    u16* Rp  = (u16*)(ws + 2097152);        // 256 KB, live: -> norm
    u16* Xb  = (u16*)(ws + 2359296);        // 16 MB,  live: -> gemm1
    u16* Wab = (u16*)(ws + 19136512);       // 6 MB,   live: -> gemm1
    u16* QKV = (u16*)(ws + 25427968);       // 48 MB,  live: gemm1 -> norm
    u16* Qn  = (u16*)(ws + 2359296);        // 16 MB,  over Xb (dead), norm -> attn
    u16* Kn  = (u16*)(ws + 75759616);       // 16 MB,  norm -> attn
    u16* Vt  = (u16*)(ws + 92536832);       // 16 MB,  norm -> attn  [bh][d][t]
    u16* Yb  = (u16*)(ws + 25427968);       // 16 MB,  over QKV (dead), attn -> gemm2

    cast_f32_bf16<<<8192, 256, 0, stream>>>(x, Xb, 2097152);
    cast_f32_bf16<<<3072, 256, 0, stream>>>(w_attn, Wab, 786432);
    cast_f32_bf16<<<1024, 256, 0, stream>>>(w_proj, Wpb, 262144);
    rope_tab<<<256, 256, 0, stream>>>(Rp);
    gemm_bt<u16><<<dim3(24, 64), 256, 0, stream>>>(Xb, Wab, QKV, 8192, 3072, 1024);
    norm_rope<<<2048, 256, 0, stream>>>(QKV, Qn, Kn, Vt, Rp);
    attn_fwd2<<<512, 256, 0, stream>>>(Qn, Kn, Vt, Yb);
    gemm_bt<float><<<dim3(8, 64), 256, 0, stream>>>(Yb, Wpb, out, 8192, 1024, 1024);
}

// Round 6
// 321.725 us; speedup vs baseline: 1.2174x; 1.0127x over previous
//
#include <hip/hip_runtime.h>

typedef unsigned short u16;
typedef unsigned int u32;
typedef __attribute__((ext_vector_type(4))) int v4i;
typedef __attribute__((ext_vector_type(4))) float f32x4;
typedef __attribute__((ext_vector_type(16))) float f32x16;
typedef __attribute__((ext_vector_type(4))) u16 v4u;
typedef __attribute__((ext_vector_type(2))) u32 u32x2;
typedef __attribute__((ext_vector_type(8))) __bf16 bf16x8;

#define B_ 4
#define T_ 2048
#define C_ 1024
#define H_ 16
#define HD_ 64
#define C3_ 3072

__device__ __forceinline__ u16 f2b(float f) {
    unsigned u = __builtin_bit_cast(unsigned, f);
    u += 0x7FFFu + ((u >> 16) & 1u);
    return (u16)(u >> 16);
}
__device__ __forceinline__ float b2f(u16 h) {
    unsigned u = ((unsigned)h) << 16;
    return __builtin_bit_cast(float, u);
}
// native-cast pack: compiler lowers to hw bf16 cvt (RNE, same as f2b)
__device__ __forceinline__ u32 pk2(float lo, float hi) {
    __bf16 a = (__bf16)lo, b = (__bf16)hi;
    return (u32)__builtin_bit_cast(u16, a) | ((u32)__builtin_bit_cast(u16, b) << 16);
}

// ---------------- cast f32 -> bf16 ----------------
__global__ __launch_bounds__(256) void cast_f32_bf16(const float* __restrict__ in,
                                                     u16* __restrict__ out, int n4) {
    int i = blockIdx.x * 256 + threadIdx.x;
    if (i >= n4) return;
    f32x4 v = *(const f32x4*)(in + (size_t)i * 4);
    v4u o;
    o[0] = f2b(v[0]); o[1] = f2b(v[1]); o[2] = f2b(v[2]); o[3] = f2b(v[3]);
    *(v4u*)(out + (size_t)i * 4) = o;
}

// ---------------- rope table ----------------
__global__ __launch_bounds__(256) void rope_tab(u16* __restrict__ rope) {
    int id = blockIdx.x * 256 + threadIdx.x;   // T_*32 entries
    int t = id >> 5, j = id & 31;
    float invf = exp2f(-(float)j * (13.287712379549449f / 32.0f));  // 10000^(-j/32)
    float fr = (float)t * invf;
    float s, c;
    sincosf(fr, &s, &c);
    rope[id * 2]     = f2b(c);
    rope[id * 2 + 1] = f2b(s);
}

// ---------------- GEMM: out[m][n] = sum_k A[m][k]*Bmat[n][k] ----------------
__device__ __forceinline__ void store_out(u16* p, float v)   { *p = f2b(v); }
__device__ __forceinline__ void store_out(float* p, float v) { *p = v; }

template <typename OutT>
__global__ __launch_bounds__(256) void gemm_bt(const u16* __restrict__ A, const u16* __restrict__ Bm,
                                               OutT* __restrict__ Cout, int Mdim, int Ndim, int Kdim) {
    __shared__ u16 As[128][40];
    __shared__ u16 Bs[128][40];
    const int tid = threadIdx.x;
    const int row0 = blockIdx.y * 128;
    const int col0 = blockIdx.x * 128;
    const int w = tid >> 6, lane = tid & 63;
    const int wm = w >> 1, wn = w & 1;
    const int lr = lane & 15, lk = lane >> 4;

    const f32x4 zf = {0.f, 0.f, 0.f, 0.f};
    f32x4 acc[4][4];
#pragma unroll
    for (int m = 0; m < 4; m++)
#pragma unroll
        for (int n = 0; n < 4; n++) acc[m][n] = zf;

    const u16* Ab = A + (size_t)row0 * Kdim;
    const u16* Bb = Bm + (size_t)col0 * Kdim;
    const int r0 = tid >> 2, q0 = tid & 3;
    const int r1 = r0 + 64;

    for (int k0 = 0; k0 < Kdim; k0 += 32) {
        *(v4i*)&As[r0][q0 * 8] = *(const v4i*)(Ab + (size_t)r0 * Kdim + k0 + q0 * 8);
        *(v4i*)&Bs[r0][q0 * 8] = *(const v4i*)(Bb + (size_t)r0 * Kdim + k0 + q0 * 8);
        *(v4i*)&As[r1][q0 * 8] = *(const v4i*)(Ab + (size_t)r1 * Kdim + k0 + q0 * 8);
        *(v4i*)&Bs[r1][q0 * 8] = *(const v4i*)(Bb + (size_t)r1 * Kdim + k0 + q0 * 8);
        __syncthreads();
        bf16x8 af[4], bfr[4];
#pragma unroll
        for (int m = 0; m < 4; m++) af[m]  = *(const bf16x8*)&As[wm * 64 + m * 16 + lr][lk * 8];
#pragma unroll
        for (int n = 0; n < 4; n++) bfr[n] = *(const bf16x8*)&Bs[wn * 64 + n * 16 + lr][lk * 8];
#pragma unroll
        for (int m = 0; m < 4; m++)
#pragma unroll
            for (int n = 0; n < 4; n++)
                acc[m][n] = __builtin_amdgcn_mfma_f32_16x16x32_bf16(af[m], bfr[n], acc[m][n], 0, 0, 0);
        __syncthreads();
    }
#pragma unroll
    for (int m = 0; m < 4; m++)
#pragma unroll
        for (int n = 0; n < 4; n++) {
            const int rr = row0 + wm * 64 + m * 16 + lk * 4;
            const int cc = col0 + wn * 64 + n * 16 + lr;
#pragma unroll
            for (int j = 0; j < 4; j++)
                store_out(Cout + (size_t)(rr + j) * Ndim + cc, acc[m][n][j]);
        }
}

// ---------------- RMSNorm + RoPE for q,k; transpose v -> [bh][d][t] ----------
__global__ __launch_bounds__(256) void norm_rope(const u16* __restrict__ qkv, u16* __restrict__ Qn,
                                                 u16* __restrict__ Kn, u16* __restrict__ Vt,
                                                 const u16* __restrict__ rope) {
    __shared__ u16 sl[3][64][72];
    const int tid = threadIdx.x, bid = blockIdx.x;
    const int tt = bid & 31, bh = bid >> 5;
    const int b = bh >> 4, h = bh & 15;
    const int t0 = tt * 64;
    const size_t base = ((size_t)(b * T_) + t0) * C3_ + h * HD_;
#pragma unroll
    for (int i = 0; i < 6; i++) {
        int c = tid + i * 256;            // 1536 16B chunks
        int p = c >> 9, rc = c & 511;
        int r = rc >> 3, ch = rc & 7;
        *(v4i*)&sl[p][r][ch * 8] = *(const v4i*)(qkv + base + (size_t)r * C3_ + p * C_ + ch * 8);
    }
    __syncthreads();
    const int row = tid >> 2, q4 = tid & 3;  // 4 lanes per row
    const u16* rp = rope + (size_t)(t0 + row) * 64;
#pragma unroll
    for (int p = 0; p < 2; p++) {            // p=0: q, p=1: k
        float ss = 0.f;
#pragma unroll
        for (int j = 0; j < 16; j++) { float v = b2f(sl[p][row][q4 * 16 + j]); ss += v * v; }
        ss += __shfl_xor(ss, 1, 64);
        ss += __shfl_xor(ss, 2, 64);
        const float rms = rsqrtf(ss * (1.f / 64.f) + 1.1920929e-7f);
        u16* outp = (p == 0 ? Qn : Kn) + ((size_t)bh * T_ + t0 + row) * HD_;
#pragma unroll
        for (int j = 0; j < 16; j++) {
            int d = q4 * 16 + j;
            float y;
            if (d < 32) {
                float x1 = b2f(sl[p][row][d]) * rms;
                float x2 = b2f(sl[p][row][d + 32]) * rms;
                y = x1 * b2f(rp[d * 2]) + x2 * b2f(rp[d * 2 + 1]);      // x1*cos + x2*sin
            } else {
                int dd = d - 32;
                float x1 = b2f(sl[p][row][dd]) * rms;
                float x2 = b2f(sl[p][row][d]) * rms;
                y = x2 * b2f(rp[dd * 2]) - x1 * b2f(rp[dd * 2 + 1]);    // x2*cos - x1*sin
            }
            outp[d] = f2b(y);
        }
    }
    const int d = tid >> 2, tq = tid & 3;
    u16* vout = Vt + ((size_t)bh * HD_ + d) * T_ + t0 + tq * 16;
#pragma unroll
    for (int jj = 0; jj < 4; jj++) {
        v4u pk;
#pragma unroll
        for (int j2 = 0; j2 < 4; j2++) pk[j2] = sl[2][tq * 16 + jj * 4 + j2][d];
        *(v4u*)(vout + jj * 4) = pk;
    }
}

// ---------------- causal flash attention v3 ----------------
// 1 warp = 1 q-tile (32 rows), KVBLK=32, no LDS, K-prefetch + early V loads.
// grid 1024: gid = blk*64 + bh (same-bh blocks share an XCD: gid%8 = bh%8).
// Block-balanced q-tile map: warps of block blk get {2blk, 2blk+1, 63-2blk, 62-2blk}.
__global__ __launch_bounds__(256) void attn_fwd3(const u16* __restrict__ Qn, const u16* __restrict__ Kn,
                                                 const u16* __restrict__ Vt, u16* __restrict__ Yb) {
    const int tid = threadIdx.x;
    const int w = tid >> 6, lane = tid & 63, la = lane & 31, hi = lane >> 5;
    const int gid = blockIdx.x;
    const int bh = gid & 63, blk = gid >> 6;
    const int b = bh >> 4, h = bh & 15;
    const int qt = (w & 2) ? (63 - 2 * blk - (w & 1)) : (2 * blk + (w & 1));
    const int q0 = qt * 32;
    const int q = q0 + la;
    const u16* Qp = Qn + (size_t)bh * T_ * HD_;
    const u16* Kp = Kn + (size_t)bh * T_ * HD_;
    const u16* Vp = Vt + (size_t)bh * HD_ * T_;
    const float SC = 0.125f * 1.44269504088896341f;   // scale * log2(e)

    bf16x8 qf[4];
#pragma unroll
    for (int c = 0; c < 4; c++)
        qf[c] = *(const bf16x8*)(Qp + (size_t)q * HD_ + c * 16 + hi * 8);

    f32x16 O0, O1;
#pragma unroll
    for (int r = 0; r < 16; r++) { O0[r] = 0.f; O1[r] = 0.f; }
    float m = -3e38f, l = 0.f;
    const int ntile = qt + 1;

    // preload K fragments for tile 0
    bf16x8 kf[4];
#pragma unroll
    for (int c = 0; c < 4; c++)
        kf[c] = *(const bf16x8*)(Kp + (size_t)la * HD_ + c * 16 + hi * 8);

    for (int kt = 0; kt < ntile; kt++) {
        const int kv0 = kt * 32;
        // QK^T (swapped): s col = query (la), rows = keys kv0 + cr(r,hi)
        f32x16 s;
#pragma unroll
        for (int r = 0; r < 16; r++) s[r] = 0.f;
#pragma unroll
        for (int c = 0; c < 4; c++)
            s = __builtin_amdgcn_mfma_f32_32x32x16_bf16(kf[c], qf[c], s, 0, 0, 0);
        // V loads for THIS tile, issued before K-prefetch (PV waits vmcnt(4))
        bf16x8 vfa[2], vfb[2];
#pragma unroll
        for (int ks = 0; ks < 2; ks++) {
            vfa[ks] = *(const bf16x8*)(Vp + (size_t)la * T_ + kv0 + ks * 16 + hi * 8);
            vfb[ks] = *(const bf16x8*)(Vp + (size_t)(32 + la) * T_ + kv0 + ks * 16 + hi * 8);
        }
        // K prefetch for next tile (stays in flight through softmax + PV)
        bf16x8 kn[4];
        if (kt + 1 < ntile) {
#pragma unroll
            for (int c = 0; c < 4; c++)
                kn[c] = *(const bf16x8*)(Kp + (size_t)(kv0 + 32 + la) * HD_ + c * 16 + hi * 8);
        }
        // causal mask on the diagonal tile
        if (kt == ntile - 1) {
#pragma unroll
            for (int r = 0; r < 16; r++) {
                const int cr = (r & 3) + 8 * (r >> 2) + 4 * hi;
                if (kv0 + cr > q) s[r] = -3e38f;
            }
        }
        // row max (lane-local 15 fmax + one cross-half exchange)
        float mx = s[0];
#pragma unroll
        for (int r = 1; r < 16; r++) mx = fmaxf(mx, s[r]);
        mx = fmaxf(mx, __shfl_xor(mx, 32, 64));
        // T13 defer-max
        if (__ballot(mx > m + 16.6355324f)) {   // 3.0/SC
            const float mn = fmaxf(m, mx);
            const float al = exp2f((m - mn) * SC);
            m = mn;
            l *= al;
            O0 *= al;
            O1 *= al;
        }
        const float nm = -m * SC;
        float p[16];
        float ps = 0.f;
#pragma unroll
        for (int r = 0; r < 16; r++) {
            p[r] = exp2f(fmaf(s[r], SC, nm));
            ps += p[r];
        }
        ps += __shfl_xor(ps, 32, 64);
        l += ps;
        // pack P into PV B-fragments (verified layout from R5)
        u32 P2[8], sh[8];
#pragma unroll
        for (int j = 0; j < 8; j++) P2[j] = pk2(p[2 * j], p[2 * j + 1]);
#pragma unroll
        for (int j = 0; j < 8; j++) sh[j] = (u32)__shfl_xor((int)P2[j], 32, 64);
        v4i w0, w1;
        if (hi == 0) {
            w0[0] = P2[0]; w0[1] = P2[1]; w0[2] = sh[0]; w0[3] = sh[1];
            w1[0] = P2[4]; w1[1] = P2[5]; w1[2] = sh[4]; w1[3] = sh[5];
        } else {
            w0[0] = sh[2]; w0[1] = sh[3]; w0[2] = P2[2]; w0[3] = P2[3];
            w1[0] = sh[6]; w1[1] = sh[7]; w1[2] = P2[6]; w1[3] = P2[7];
        }
        const bf16x8 pa0 = __builtin_bit_cast(bf16x8, w0);
        const bf16x8 pa1 = __builtin_bit_cast(bf16x8, w1);
        O0 = __builtin_amdgcn_mfma_f32_32x32x16_bf16(vfa[0], pa0, O0, 0, 0, 0);
        O0 = __builtin_amdgcn_mfma_f32_32x32x16_bf16(vfa[1], pa1, O0, 0, 0, 0);
        O1 = __builtin_amdgcn_mfma_f32_32x32x16_bf16(vfb[0], pa0, O1, 0, 0, 0);
        O1 = __builtin_amdgcn_mfma_f32_32x32x16_bf16(vfb[1], pa1, O1, 0, 0, 0);
#pragma unroll
        for (int c = 0; c < 4; c++) kf[c] = kn[c];
    }
    const float inv = 1.f / l;
    u16* yrow = Yb + ((size_t)(b * T_) + q) * C_ + h * HD_;
#pragma unroll
    for (int r4 = 0; r4 < 4; r4++) {
        u32x2 st0, st1;
        st0[0] = pk2(O0[r4 * 4 + 0] * inv, O0[r4 * 4 + 1] * inv);
        st0[1] = pk2(O0[r4 * 4 + 2] * inv, O0[r4 * 4 + 3] * inv);
        st1[0] = pk2(O1[r4 * 4 + 0] * inv, O1[r4 * 4 + 1] * inv);
        st1[1] = pk2(O1[r4 * 4 + 2] * inv, O1[r4 * 4 + 3] * inv);
        *(u32x2*)(yrow + r4 * 8 + hi * 4)      = st0;
        *(u32x2*)(yrow + 32 + r4 * 8 + hi * 4) = st1;
    }
}

extern "C" void kernel_launch(void* const* d_in, const int* in_sizes, int n_in,
                              void* d_out, int out_size, void* d_ws, size_t ws_size,
                              hipStream_t stream) {
    const float* x      = (const float*)d_in[0];
    const float* w_attn = (const float*)d_in[1];
    const float* w_proj = (const float*)d_in[2];
    float* out = (float*)d_out;
    char* ws = (char*)d_ws;
    // lifetime-overlapped workspace, peak ~104.3 MB
    u16* Wpb = (u16*)(ws + 0);              // 2 MB,   live: all
    u16* Rp  = (u16*)(ws + 2097152);        // 256 KB, live: -> norm
    u16* Xb  = (u16*)(ws + 2359296);        // 16 MB,  live: -> gemm1
    u16* Wab = (u16*)(ws + 19136512);       // 6 MB,   live: -> gemm1
    u16* QKV = (u16*)(ws + 25427968);       // 48 MB,  live: gemm1 -> norm
    u16* Qn  = (u16*)(ws + 2359296);        // 16 MB,  over Xb (dead), norm -> attn
    u16* Kn  = (u16*)(ws + 75759616);       // 16 MB,  norm -> attn
    u16* Vt  = (u16*)(ws + 92536832);       // 16 MB,  norm -> attn  [bh][d][t]
    u16* Yb  = (u16*)(ws + 25427968);       // 16 MB,  over QKV (dead), attn -> gemm2

    cast_f32_bf16<<<8192, 256, 0, stream>>>(x, Xb, 2097152);
    cast_f32_bf16<<<3072, 256, 0, stream>>>(w_attn, Wab, 786432);
    cast_f32_bf16<<<1024, 256, 0, stream>>>(w_proj, Wpb, 262144);
    rope_tab<<<256, 256, 0, stream>>>(Rp);
    gemm_bt<u16><<<dim3(24, 64), 256, 0, stream>>>(Xb, Wab, QKV, 8192, 3072, 1024);
    norm_rope<<<2048, 256, 0, stream>>>(QKV, Qn, Kn, Vt, Rp);
    attn_fwd3<<<1024, 256, 0, stream>>>(Qn, Kn, Vt, Yb);
    gemm_bt<float><<<dim3(8, 64), 256, 0, stream>>>(Yb, Wpb, out, 8192, 1024, 1024);
}

// Round 7
// 284.836 us; speedup vs baseline: 1.3751x; 1.1295x over previous
//
#include <hip/hip_runtime.h>

typedef unsigned short u16;
typedef unsigned int u32;
typedef __attribute__((ext_vector_type(4))) int v4i;
typedef __attribute__((ext_vector_type(4))) float f32x4;
typedef __attribute__((ext_vector_type(16))) float f32x16;
typedef __attribute__((ext_vector_type(4))) u16 v4u;
typedef __attribute__((ext_vector_type(2))) u32 u32x2;
typedef __attribute__((ext_vector_type(8))) __bf16 bf16x8;

#define B_ 4
#define T_ 2048
#define C_ 1024
#define H_ 16
#define HD_ 64
#define C3_ 3072

__device__ __forceinline__ u16 f2b(float f) {
    unsigned u = __builtin_bit_cast(unsigned, f);
    u += 0x7FFFu + ((u >> 16) & 1u);
    return (u16)(u >> 16);
}
__device__ __forceinline__ float b2f(u16 h) {
    unsigned u = ((unsigned)h) << 16;
    return __builtin_bit_cast(float, u);
}
__device__ __forceinline__ u32 pk2(float lo, float hi) {
    __bf16 a = (__bf16)lo, b = (__bf16)hi;
    return (u32)__builtin_bit_cast(u16, a) | ((u32)__builtin_bit_cast(u16, b) << 16);
}

// ---------------- cast f32 -> bf16 ----------------
__global__ __launch_bounds__(256) void cast_f32_bf16(const float* __restrict__ in,
                                                     u16* __restrict__ out, int n4) {
    int i = blockIdx.x * 256 + threadIdx.x;
    if (i >= n4) return;
    f32x4 v = *(const f32x4*)(in + (size_t)i * 4);
    v4u o;
    o[0] = f2b(v[0]); o[1] = f2b(v[1]); o[2] = f2b(v[2]); o[3] = f2b(v[3]);
    *(v4u*)(out + (size_t)i * 4) = o;
}

// ---------------- rope table ----------------
__global__ __launch_bounds__(256) void rope_tab(u16* __restrict__ rope) {
    int id = blockIdx.x * 256 + threadIdx.x;   // T_*32 entries
    int t = id >> 5, j = id & 31;
    float invf = exp2f(-(float)j * (13.287712379549449f / 32.0f));  // 10000^(-j/32)
    float fr = (float)t * invf;
    float s, c;
    sincosf(fr, &s, &c);
    rope[id * 2]     = f2b(c);
    rope[id * 2 + 1] = f2b(s);
}

// ---------------- GEMM: out[m][n] = sum_k A[m][k]*Bmat[n][k] ----------------
__device__ __forceinline__ void store_out(u16* p, float v)   { *p = f2b(v); }
__device__ __forceinline__ void store_out(float* p, float v) { *p = v; }

template <typename OutT>
__global__ __launch_bounds__(256) void gemm_bt(const u16* __restrict__ A, const u16* __restrict__ Bm,
                                               OutT* __restrict__ Cout, int Mdim, int Ndim, int Kdim) {
    __shared__ u16 As[128][40];
    __shared__ u16 Bs[128][40];
    const int tid = threadIdx.x;
    const int row0 = blockIdx.y * 128;
    const int col0 = blockIdx.x * 128;
    const int w = tid >> 6, lane = tid & 63;
    const int wm = w >> 1, wn = w & 1;
    const int lr = lane & 15, lk = lane >> 4;

    const f32x4 zf = {0.f, 0.f, 0.f, 0.f};
    f32x4 acc[4][4];
#pragma unroll
    for (int m = 0; m < 4; m++)
#pragma unroll
        for (int n = 0; n < 4; n++) acc[m][n] = zf;

    const u16* Ab = A + (size_t)row0 * Kdim;
    const u16* Bb = Bm + (size_t)col0 * Kdim;
    const int r0 = tid >> 2, q0 = tid & 3;
    const int r1 = r0 + 64;

    for (int k0 = 0; k0 < Kdim; k0 += 32) {
        *(v4i*)&As[r0][q0 * 8] = *(const v4i*)(Ab + (size_t)r0 * Kdim + k0 + q0 * 8);
        *(v4i*)&Bs[r0][q0 * 8] = *(const v4i*)(Bb + (size_t)r0 * Kdim + k0 + q0 * 8);
        *(v4i*)&As[r1][q0 * 8] = *(const v4i*)(Ab + (size_t)r1 * Kdim + k0 + q0 * 8);
        *(v4i*)&Bs[r1][q0 * 8] = *(const v4i*)(Bb + (size_t)r1 * Kdim + k0 + q0 * 8);
        __syncthreads();
        bf16x8 af[4], bfr[4];
#pragma unroll
        for (int m = 0; m < 4; m++) af[m]  = *(const bf16x8*)&As[wm * 64 + m * 16 + lr][lk * 8];
#pragma unroll
        for (int n = 0; n < 4; n++) bfr[n] = *(const bf16x8*)&Bs[wn * 64 + n * 16 + lr][lk * 8];
#pragma unroll
        for (int m = 0; m < 4; m++)
#pragma unroll
            for (int n = 0; n < 4; n++)
                acc[m][n] = __builtin_amdgcn_mfma_f32_16x16x32_bf16(af[m], bfr[n], acc[m][n], 0, 0, 0);
        __syncthreads();
    }
#pragma unroll
    for (int m = 0; m < 4; m++)
#pragma unroll
        for (int n = 0; n < 4; n++) {
            const int rr = row0 + wm * 64 + m * 16 + lk * 4;
            const int cc = col0 + wn * 64 + n * 16 + lr;
#pragma unroll
            for (int j = 0; j < 4; j++)
                store_out(Cout + (size_t)(rr + j) * Ndim + cc, acc[m][n][j]);
        }
}

// ---------------- RMSNorm + RoPE for q,k; transpose v -> [bh][d][t] ----------
__global__ __launch_bounds__(256) void norm_rope(const u16* __restrict__ qkv, u16* __restrict__ Qn,
                                                 u16* __restrict__ Kn, u16* __restrict__ Vt,
                                                 const u16* __restrict__ rope) {
    __shared__ u16 sl[3][64][72];
    const int tid = threadIdx.x, bid = blockIdx.x;
    const int tt = bid & 31, bh = bid >> 5;
    const int b = bh >> 4, h = bh & 15;
    const int t0 = tt * 64;
    const size_t base = ((size_t)(b * T_) + t0) * C3_ + h * HD_;
#pragma unroll
    for (int i = 0; i < 6; i++) {
        int c = tid + i * 256;            // 1536 16B chunks
        int p = c >> 9, rc = c & 511;
        int r = rc >> 3, ch = rc & 7;
        *(v4i*)&sl[p][r][ch * 8] = *(const v4i*)(qkv + base + (size_t)r * C3_ + p * C_ + ch * 8);
    }
    __syncthreads();
    const int row = tid >> 2, q4 = tid & 3;  // 4 lanes per row
    const u16* rp = rope + (size_t)(t0 + row) * 64;
#pragma unroll
    for (int p = 0; p < 2; p++) {            // p=0: q, p=1: k
        float ss = 0.f;
#pragma unroll
        for (int j = 0; j < 16; j++) { float v = b2f(sl[p][row][q4 * 16 + j]); ss += v * v; }
        ss += __shfl_xor(ss, 1, 64);
        ss += __shfl_xor(ss, 2, 64);
        const float rms = rsqrtf(ss * (1.f / 64.f) + 1.1920929e-7f);
        u16* outp = (p == 0 ? Qn : Kn) + ((size_t)bh * T_ + t0 + row) * HD_;
#pragma unroll
        for (int j = 0; j < 16; j++) {
            int d = q4 * 16 + j;
            float y;
            if (d < 32) {
                float x1 = b2f(sl[p][row][d]) * rms;
                float x2 = b2f(sl[p][row][d + 32]) * rms;
                y = x1 * b2f(rp[d * 2]) + x2 * b2f(rp[d * 2 + 1]);      // x1*cos + x2*sin
            } else {
                int dd = d - 32;
                float x1 = b2f(sl[p][row][dd]) * rms;
                float x2 = b2f(sl[p][row][d]) * rms;
                y = x2 * b2f(rp[dd * 2]) - x1 * b2f(rp[dd * 2 + 1]);    // x2*cos - x1*sin
            }
            outp[d] = f2b(y);
        }
    }
    const int d = tid >> 2, tq = tid & 3;
    u16* vout = Vt + ((size_t)bh * HD_ + d) * T_ + t0 + tq * 16;
#pragma unroll
    for (int jj = 0; jj < 4; jj++) {
        v4u pk;
#pragma unroll
        for (int j2 = 0; j2 < 4; j2++) pk[j2] = sl[2][tq * 16 + jj * 4 + j2][d];
        *(v4u*)(vout + jj * 4) = pk;
    }
}

// ---------------- causal flash attention v4: block-cooperative LDS staging ---
// Block = 4 waves = 128 contiguous q-rows; all waves sweep the same K/V tiles.
// K/V tiles staged coalesced into LDS with T2 XOR swizzle (rows are 128B).
// grid 1024: gid = (15-qb)*64 + bh  (heavy blocks first; bh%8 spreads XCDs).
__global__ __launch_bounds__(256) void attn_fwd4(const u16* __restrict__ Qn, const u16* __restrict__ Kn,
                                                 const u16* __restrict__ Vt, u16* __restrict__ Yb) {
    __shared__ u16 Ks[64 * 64];
    __shared__ u16 Vs[64 * 64];
    const int tid = threadIdx.x;
    const int w = tid >> 6, lane = tid & 63, la = lane & 31, hi = lane >> 5;
    const int gid = blockIdx.x;
    const int bh = gid & 63, qb = 15 - (gid >> 6);
    const int b = bh >> 4, h = bh & 15;
    const int q0w = qb * 128 + w * 32;
    const int q = q0w + la;
    const u16* Qp = Qn + (size_t)bh * T_ * HD_;
    const u16* Kp = Kn + (size_t)bh * T_ * HD_;
    const u16* Vp = Vt + (size_t)bh * HD_ * T_;
    const float SC = 0.125f * 1.44269504088896341f;   // scale * log2(e)

    bf16x8 qf[4];
#pragma unroll
    for (int c = 0; c < 4; c++)
        qf[c] = *(const bf16x8*)(Qp + (size_t)q * HD_ + c * 16 + hi * 8);

    f32x16 O0, O1;
#pragma unroll
    for (int r = 0; r < 16; r++) { O0[r] = 0.f; O1[r] = 0.f; }
    float m = -3e38f, l = 0.f;
    const int lastt = q0w >> 6;
    const int ntile = 2 * qb + 2;
    // staging coords: thread handles chunks c and c+256 of 512 (16B each)
    const int srow0 = tid >> 3, scol = (tid & 7) * 8;            // u16 units
    const int srow1 = srow0 + 32;
    const int sw0 = srow0 * 64 + (scol ^ ((srow0 & 7) << 3));
    const int sw1 = srow1 * 64 + (scol ^ ((srow1 & 7) << 3));
    const int swl = (la & 7) << 3;                               // frag-read XOR

    for (int kt = 0; kt < ntile; kt++) {
        const int kv0 = kt * 64;
        __syncthreads();
        *(v4i*)&Ks[sw0] = *(const v4i*)(Kp + (size_t)(kv0 + srow0) * HD_ + scol);
        *(v4i*)&Ks[sw1] = *(const v4i*)(Kp + (size_t)(kv0 + srow1) * HD_ + scol);
        *(v4i*)&Vs[sw0] = *(const v4i*)(Vp + (size_t)srow0 * T_ + kv0 + scol);
        *(v4i*)&Vs[sw1] = *(const v4i*)(Vp + (size_t)srow1 * T_ + kv0 + scol);
        __syncthreads();
        if (kv0 > q0w + 31) continue;      // past this wave's diagonal (barrier counts stay matched)
        // QK^T (swapped): s cols = queries (la), rows = keys
        f32x16 s0, s1;
#pragma unroll
        for (int r = 0; r < 16; r++) { s0[r] = 0.f; s1[r] = 0.f; }
#pragma unroll
        for (int c = 0; c < 4; c++) {
            const int cb = c * 16 + hi * 8;
            bf16x8 kfa = *(const bf16x8*)&Ks[la * 64 + (cb ^ swl)];
            bf16x8 kfb = *(const bf16x8*)&Ks[(32 + la) * 64 + (cb ^ swl)];
            s0 = __builtin_amdgcn_mfma_f32_32x32x16_bf16(kfa, qf[c], s0, 0, 0, 0);
            s1 = __builtin_amdgcn_mfma_f32_32x32x16_bf16(kfb, qf[c], s1, 0, 0, 0);
        }
        if (kt == lastt) {
#pragma unroll
            for (int r = 0; r < 16; r++) {
                const int cr = (r & 3) + 8 * (r >> 2) + 4 * hi;
                if (kv0 + cr > q)      s0[r] = -3e38f;
                if (kv0 + 32 + cr > q) s1[r] = -3e38f;
            }
        }
        float mx = fmaxf(s0[0], s1[0]);
#pragma unroll
        for (int r = 1; r < 16; r++) mx = fmaxf(mx, fmaxf(s0[r], s1[r]));
        mx = fmaxf(mx, __shfl_xor(mx, 32, 64));
        if (__ballot(mx > m + 16.6355324f)) {   // T13 defer-max (3.0/SC)
            const float mn = fmaxf(m, mx);
            const float al = exp2f((m - mn) * SC);
            m = mn;
            l *= al;
            O0 *= al;
            O1 *= al;
        }
        const float nm = -m * SC;
        float p0[16], p1[16];
        float ps = 0.f;
#pragma unroll
        for (int r = 0; r < 16; r++) {
            p0[r] = exp2f(fmaf(s0[r], SC, nm));
            p1[r] = exp2f(fmaf(s1[r], SC, nm));
            ps += p0[r] + p1[r];
        }
        l += ps;                     // per-lane partial; cross-half merge after loop
#pragma unroll
        for (int g = 0; g < 2; g++) {
            u32 P2[8], sh[8];
#pragma unroll
            for (int j = 0; j < 8; j++)
                P2[j] = g ? pk2(p1[2 * j], p1[2 * j + 1]) : pk2(p0[2 * j], p0[2 * j + 1]);
#pragma unroll
            for (int j = 0; j < 8; j++) sh[j] = (u32)__shfl_xor((int)P2[j], 32, 64);
            v4i w0, w1;
            if (hi == 0) {
                w0[0] = P2[0]; w0[1] = P2[1]; w0[2] = sh[0]; w0[3] = sh[1];
                w1[0] = P2[4]; w1[1] = P2[5]; w1[2] = sh[4]; w1[3] = sh[5];
            } else {
                w0[0] = sh[2]; w0[1] = sh[3]; w0[2] = P2[2]; w0[3] = P2[3];
                w1[0] = sh[6]; w1[1] = sh[7]; w1[2] = P2[6]; w1[3] = P2[7];
            }
            const bf16x8 pa0 = __builtin_bit_cast(bf16x8, w0);
            const bf16x8 pa1 = __builtin_bit_cast(bf16x8, w1);
#pragma unroll
            for (int ks = 0; ks < 2; ks++) {
                const bf16x8 pa = ks ? pa1 : pa0;
                const int cb = g * 32 + ks * 16 + hi * 8;
                bf16x8 vfa = *(const bf16x8*)&Vs[la * 64 + (cb ^ swl)];
                bf16x8 vfb = *(const bf16x8*)&Vs[(32 + la) * 64 + (cb ^ swl)];
                O0 = __builtin_amdgcn_mfma_f32_32x32x16_bf16(vfa, pa, O0, 0, 0, 0);
                O1 = __builtin_amdgcn_mfma_f32_32x32x16_bf16(vfb, pa, O1, 0, 0, 0);
            }
        }
    }
    l += __shfl_xor(l, 32, 64);
    const float inv = 1.f / l;
    u16* yrow = Yb + ((size_t)(b * T_) + q) * C_ + h * HD_;
#pragma unroll
    for (int r4 = 0; r4 < 4; r4++) {
        u32x2 st0, st1;
        st0[0] = pk2(O0[r4 * 4 + 0] * inv, O0[r4 * 4 + 1] * inv);
        st0[1] = pk2(O0[r4 * 4 + 2] * inv, O0[r4 * 4 + 3] * inv);
        st1[0] = pk2(O1[r4 * 4 + 0] * inv, O1[r4 * 4 + 1] * inv);
        st1[1] = pk2(O1[r4 * 4 + 2] * inv, O1[r4 * 4 + 3] * inv);
        *(u32x2*)(yrow + r4 * 8 + hi * 4)      = st0;
        *(u32x2*)(yrow + 32 + r4 * 8 + hi * 4) = st1;
    }
}

extern "C" void kernel_launch(void* const* d_in, const int* in_sizes, int n_in,
                              void* d_out, int out_size, void* d_ws, size_t ws_size,
                              hipStream_t stream) {
    const float* x      = (const float*)d_in[0];
    const float* w_attn = (const float*)d_in[1];
    const float* w_proj = (const float*)d_in[2];
    float* out = (float*)d_out;
    char* ws = (char*)d_ws;
    // lifetime-overlapped workspace, peak ~104.3 MB
    u16* Wpb = (u16*)(ws + 0);              // 2 MB,   live: all
    u16* Rp  = (u16*)(ws + 2097152);        // 256 KB, live: -> norm
    u16* Xb  = (u16*)(ws + 2359296);        // 16 MB,  live: -> gemm1
    u16* Wab = (u16*)(ws + 19136512);       // 6 MB,   live: -> gemm1
    u16* QKV = (u16*)(ws + 25427968);       // 48 MB,  live: gemm1 -> norm
    u16* Qn  = (u16*)(ws + 2359296);        // 16 MB,  over Xb (dead), norm -> attn
    u16* Kn  = (u16*)(ws + 75759616);       // 16 MB,  norm -> attn
    u16* Vt  = (u16*)(ws + 92536832);       // 16 MB,  norm -> attn  [bh][d][t]
    u16* Yb  = (u16*)(ws + 25427968);       // 16 MB,  over QKV (dead), attn -> gemm2

    cast_f32_bf16<<<8192, 256, 0, stream>>>(x, Xb, 2097152);
    cast_f32_bf16<<<3072, 256, 0, stream>>>(w_attn, Wab, 786432);
    cast_f32_bf16<<<1024, 256, 0, stream>>>(w_proj, Wpb, 262144);
    rope_tab<<<256, 256, 0, stream>>>(Rp);
    gemm_bt<u16><<<dim3(24, 64), 256, 0, stream>>>(Xb, Wab, QKV, 8192, 3072, 1024);
    norm_rope<<<2048, 256, 0, stream>>>(QKV, Qn, Kn, Vt, Rp);
    attn_fwd4<<<1024, 256, 0, stream>>>(Qn, Kn, Vt, Yb);
    gemm_bt<float><<<dim3(8, 64), 256, 0, stream>>>(Yb, Wpb, out, 8192, 1024, 1024);
}

// Round 8
// 274.071 us; speedup vs baseline: 1.4291x; 1.0393x over previous
//
#include <hip/hip_runtime.h>

typedef unsigned short u16;
typedef unsigned int u32;
typedef __attribute__((ext_vector_type(4))) int v4i;
typedef __attribute__((ext_vector_type(4))) float f32x4;
typedef __attribute__((ext_vector_type(16))) float f32x16;
typedef __attribute__((ext_vector_type(4))) u16 v4u;
typedef __attribute__((ext_vector_type(2))) u32 u32x2;
typedef __attribute__((ext_vector_type(8))) __bf16 bf16x8;

#define B_ 4
#define T_ 2048
#define C_ 1024
#define H_ 16
#define HD_ 64
#define C3_ 3072

__device__ __forceinline__ u16 f2b(float f) {
    unsigned u = __builtin_bit_cast(unsigned, f);
    u += 0x7FFFu + ((u >> 16) & 1u);
    return (u16)(u >> 16);
}
__device__ __forceinline__ float b2f(u16 h) {
    unsigned u = ((unsigned)h) << 16;
    return __builtin_bit_cast(float, u);
}
__device__ __forceinline__ u32 pk2(float lo, float hi) {
    __bf16 a = (__bf16)lo, b = (__bf16)hi;
    return (u32)__builtin_bit_cast(u16, a) | ((u32)__builtin_bit_cast(u16, b) << 16);
}
// async global->LDS, 16B per lane; LDS dest = uniform base + lane*16
__device__ __forceinline__ void glds16(const u16* g, u16* l) {
    __builtin_amdgcn_global_load_lds((const __attribute__((address_space(1))) void*)g,
                                     (__attribute__((address_space(3))) void*)l, 16, 0, 0);
}

// ---------------- cast f32 -> bf16 ----------------
__global__ __launch_bounds__(256) void cast_f32_bf16(const float* __restrict__ in,
                                                     u16* __restrict__ out, int n4) {
    int i = blockIdx.x * 256 + threadIdx.x;
    if (i >= n4) return;
    f32x4 v = *(const f32x4*)(in + (size_t)i * 4);
    v4u o;
    o[0] = f2b(v[0]); o[1] = f2b(v[1]); o[2] = f2b(v[2]); o[3] = f2b(v[3]);
    *(v4u*)(out + (size_t)i * 4) = o;
}

// ---------------- rope table ----------------
__global__ __launch_bounds__(256) void rope_tab(u16* __restrict__ rope) {
    int id = blockIdx.x * 256 + threadIdx.x;   // T_*32 entries
    int t = id >> 5, j = id & 31;
    float invf = exp2f(-(float)j * (13.287712379549449f / 32.0f));  // 10000^(-j/32)
    float fr = (float)t * invf;
    float s, c;
    sincosf(fr, &s, &c);
    rope[id * 2]     = f2b(c);
    rope[id * 2 + 1] = f2b(s);
}

// ---------------- GEMM v2 (m97 structure): global_load_lds + swizzled LDS ----
// out[m][n] = sum_k A[m][k]*Bmat[n][k].  LDS [128][32] u16 linear, swizzle
// ch' = ch ^ ((row>>1)&3)  (applied on the GLOBAL source; read applies same XOR).
__device__ __forceinline__ void store_out(u16* p, float v)   { *p = f2b(v); }
__device__ __forceinline__ void store_out(float* p, float v) { *p = v; }

template <typename OutT>
__global__ __launch_bounds__(256) void gemm_bt2(const u16* __restrict__ A, const u16* __restrict__ Bm,
                                                OutT* __restrict__ Cout, int Mdim, int Ndim, int Kdim) {
    __shared__ u16 As[4096];     // [128][32] swizzled
    __shared__ u16 Bs[4096];
    const int tid = threadIdx.x;
    const int row0 = blockIdx.y * 128;
    const int col0 = blockIdx.x * 128;
    const int w = tid >> 6, lane = tid & 63;
    const int wm = w >> 1, wn = w & 1;
    const int lr = lane & 15, lk = lane >> 4;

    const f32x4 zf = {0.f, 0.f, 0.f, 0.f};
    f32x4 acc[4][4];
#pragma unroll
    for (int m = 0; m < 4; m++)
#pragma unroll
        for (int n = 0; n < 4; n++) acc[m][n] = zf;

    const u16* Ab = A + (size_t)row0 * Kdim;
    const u16* Bb = Bm + (size_t)col0 * Kdim;
    // staging: wave w covers rows [w*32, w*32+32); inst i covers 16 rows.
    const int r0 = w * 32 + (lane >> 2);
    const int r1 = r0 + 16;
    const int ch0 = (lane & 3) ^ ((r0 >> 1) & 3);
    const int ch1 = (lane & 3) ^ ((r1 >> 1) & 3);
    const size_t ga0 = (size_t)r0 * Kdim + ch0 * 8;
    const size_t ga1 = (size_t)r1 * Kdim + ch1 * 8;
    u16* la0 = As + w * 1024;
    u16* la1 = As + w * 1024 + 512;
    u16* lb0 = Bs + w * 1024;
    u16* lb1 = Bs + w * 1024 + 512;
    // fragment read column slot (same XOR), loop-invariant
    const int chx = ((lk ^ ((lr >> 1) & 3)) * 8);

    for (int k0 = 0; k0 < Kdim; k0 += 32) {
        glds16(Ab + ga0 + k0, la0);
        glds16(Ab + ga1 + k0, la1);
        glds16(Bb + ga0 + k0, lb0);
        glds16(Bb + ga1 + k0, lb1);
        __syncthreads();
        bf16x8 af[4], bfr[4];
#pragma unroll
        for (int m = 0; m < 4; m++) af[m]  = *(const bf16x8*)&As[(wm * 64 + m * 16 + lr) * 32 + chx];
#pragma unroll
        for (int n = 0; n < 4; n++) bfr[n] = *(const bf16x8*)&Bs[(wn * 64 + n * 16 + lr) * 32 + chx];
#pragma unroll
        for (int m = 0; m < 4; m++)
#pragma unroll
            for (int n = 0; n < 4; n++)
                acc[m][n] = __builtin_amdgcn_mfma_f32_16x16x32_bf16(af[m], bfr[n], acc[m][n], 0, 0, 0);
        __syncthreads();
    }
#pragma unroll
    for (int m = 0; m < 4; m++)
#pragma unroll
        for (int n = 0; n < 4; n++) {
            const int rr = row0 + wm * 64 + m * 16 + lk * 4;
            const int cc = col0 + wn * 64 + n * 16 + lr;
#pragma unroll
            for (int j = 0; j < 4; j++)
                store_out(Cout + (size_t)(rr + j) * Ndim + cc, acc[m][n][j]);
        }
}

// ---------------- RMSNorm + RoPE for q,k; transpose v -> [bh][d][t] ----------
__global__ __launch_bounds__(256) void norm_rope(const u16* __restrict__ qkv, u16* __restrict__ Qn,
                                                 u16* __restrict__ Kn, u16* __restrict__ Vt,
                                                 const u16* __restrict__ rope) {
    __shared__ u16 sl[3][64][72];
    const int tid = threadIdx.x, bid = blockIdx.x;
    const int tt = bid & 31, bh = bid >> 5;
    const int b = bh >> 4, h = bh & 15;
    const int t0 = tt * 64;
    const size_t base = ((size_t)(b * T_) + t0) * C3_ + h * HD_;
#pragma unroll
    for (int i = 0; i < 6; i++) {
        int c = tid + i * 256;            // 1536 16B chunks
        int p = c >> 9, rc = c & 511;
        int r = rc >> 3, ch = rc & 7;
        *(v4i*)&sl[p][r][ch * 8] = *(const v4i*)(qkv + base + (size_t)r * C3_ + p * C_ + ch * 8);
    }
    __syncthreads();
    const int row = tid >> 2, q4 = tid & 3;  // 4 lanes per row
    const u16* rp = rope + (size_t)(t0 + row) * 64;
#pragma unroll
    for (int p = 0; p < 2; p++) {            // p=0: q, p=1: k
        float ss = 0.f;
#pragma unroll
        for (int j = 0; j < 16; j++) { float v = b2f(sl[p][row][q4 * 16 + j]); ss += v * v; }
        ss += __shfl_xor(ss, 1, 64);
        ss += __shfl_xor(ss, 2, 64);
        const float rms = rsqrtf(ss * (1.f / 64.f) + 1.1920929e-7f);
        u16* outp = (p == 0 ? Qn : Kn) + ((size_t)bh * T_ + t0 + row) * HD_;
#pragma unroll
        for (int j = 0; j < 16; j++) {
            int d = q4 * 16 + j;
            float y;
            if (d < 32) {
                float x1 = b2f(sl[p][row][d]) * rms;
                float x2 = b2f(sl[p][row][d + 32]) * rms;
                y = x1 * b2f(rp[d * 2]) + x2 * b2f(rp[d * 2 + 1]);      // x1*cos + x2*sin
            } else {
                int dd = d - 32;
                float x1 = b2f(sl[p][row][dd]) * rms;
                float x2 = b2f(sl[p][row][d]) * rms;
                y = x2 * b2f(rp[dd * 2]) - x1 * b2f(rp[dd * 2 + 1]);    // x2*cos - x1*sin
            }
            outp[d] = f2b(y);
        }
    }
    const int d = tid >> 2, tq = tid & 3;
    u16* vout = Vt + ((size_t)bh * HD_ + d) * T_ + t0 + tq * 16;
#pragma unroll
    for (int jj = 0; jj < 4; jj++) {
        v4u pk;
#pragma unroll
        for (int j2 = 0; j2 < 4; j2++) pk[j2] = sl[2][tq * 16 + jj * 4 + j2][d];
        *(v4u*)(vout + jj * 4) = pk;
    }
}

// ---------------- causal flash attention v5: LDS staging + permlane pack -----
__global__ __launch_bounds__(256) void attn_fwd5(const u16* __restrict__ Qn, const u16* __restrict__ Kn,
                                                 const u16* __restrict__ Vt, u16* __restrict__ Yb) {
    __shared__ u16 Ks[64 * 64];
    __shared__ u16 Vs[64 * 64];
    const int tid = threadIdx.x;
    const int w = tid >> 6, lane = tid & 63, la = lane & 31, hi = lane >> 5;
    const int gid = blockIdx.x;
    const int bh = gid & 63, qb = 15 - (gid >> 6);
    const int b = bh >> 4, h = bh & 15;
    const int q0w = qb * 128 + w * 32;
    const int q = q0w + la;
    const u16* Qp = Qn + (size_t)bh * T_ * HD_;
    const u16* Kp = Kn + (size_t)bh * T_ * HD_;
    const u16* Vp = Vt + (size_t)bh * HD_ * T_;
    const float SC = 0.125f * 1.44269504088896341f;   // scale * log2(e)

    bf16x8 qf[4];
#pragma unroll
    for (int c = 0; c < 4; c++)
        qf[c] = *(const bf16x8*)(Qp + (size_t)q * HD_ + c * 16 + hi * 8);

    f32x16 O0, O1;
#pragma unroll
    for (int r = 0; r < 16; r++) { O0[r] = 0.f; O1[r] = 0.f; }
    float m = -3e38f, l = 0.f;
    const int lastt = q0w >> 6;
    const int ntile = 2 * qb + 2;
    const int srow0 = tid >> 3, scol = (tid & 7) * 8;            // u16 units
    const int srow1 = srow0 + 32;
    const int sw0 = srow0 * 64 + (scol ^ ((srow0 & 7) << 3));
    const int sw1 = srow1 * 64 + (scol ^ ((srow1 & 7) << 3));
    const int swl = (la & 7) << 3;                               // frag-read XOR

    for (int kt = 0; kt < ntile; kt++) {
        const int kv0 = kt * 64;
        __syncthreads();
        *(v4i*)&Ks[sw0] = *(const v4i*)(Kp + (size_t)(kv0 + srow0) * HD_ + scol);
        *(v4i*)&Ks[sw1] = *(const v4i*)(Kp + (size_t)(kv0 + srow1) * HD_ + scol);
        *(v4i*)&Vs[sw0] = *(const v4i*)(Vp + (size_t)srow0 * T_ + kv0 + scol);
        *(v4i*)&Vs[sw1] = *(const v4i*)(Vp + (size_t)srow1 * T_ + kv0 + scol);
        __syncthreads();
        if (kv0 > q0w + 31) continue;      // past diagonal; barrier counts stay matched
        f32x16 s0, s1;
#pragma unroll
        for (int r = 0; r < 16; r++) { s0[r] = 0.f; s1[r] = 0.f; }
#pragma unroll
        for (int c = 0; c < 4; c++) {
            const int cb = c * 16 + hi * 8;
            bf16x8 kfa = *(const bf16x8*)&Ks[la * 64 + (cb ^ swl)];
            bf16x8 kfb = *(const bf16x8*)&Ks[(32 + la) * 64 + (cb ^ swl)];
            s0 = __builtin_amdgcn_mfma_f32_32x32x16_bf16(kfa, qf[c], s0, 0, 0, 0);
            s1 = __builtin_amdgcn_mfma_f32_32x32x16_bf16(kfb, qf[c], s1, 0, 0, 0);
        }
        if (kt == lastt) {
#pragma unroll
            for (int r = 0; r < 16; r++) {
                const int cr = (r & 3) + 8 * (r >> 2) + 4 * hi;
                if (kv0 + cr > q)      s0[r] = -3e38f;
                if (kv0 + 32 + cr > q) s1[r] = -3e38f;
            }
        }
        float mx = fmaxf(s0[0], s1[0]);
#pragma unroll
        for (int r = 1; r < 16; r++) mx = fmaxf(mx, fmaxf(s0[r], s1[r]));
        mx = fmaxf(mx, __shfl_xor(mx, 32, 64));
        if (__ballot(mx > m + 16.6355324f)) {   // T13 defer-max (3.0/SC)
            const float mn = fmaxf(m, mx);
            const float al = exp2f((m - mn) * SC);
            m = mn;
            l *= al;
            O0 *= al;
            O1 *= al;
        }
        const float nm = -m * SC;
        float p0[16], p1[16];
        float ps = 0.f;
#pragma unroll
        for (int r = 0; r < 16; r++) {
            p0[r] = exp2f(fmaf(s0[r], SC, nm));
            p1[r] = exp2f(fmaf(s1[r], SC, nm));
            ps += p0[r] + p1[r];
        }
        l += ps;                     // per-lane partial; merged after loop
#pragma unroll
        for (int g = 0; g < 2; g++) {
            u32 P2[8];
#pragma unroll
            for (int j = 0; j < 8; j++)
                P2[j] = g ? pk2(p1[2 * j], p1[2 * j + 1]) : pk2(p0[2 * j], p0[2 * j + 1]);
            // T12: permlane32_swap redistribution (replaces 16 bpermute + selects)
            auto s02 = __builtin_amdgcn_permlane32_swap((int)P2[0], (int)P2[2], false, false);
            auto s13 = __builtin_amdgcn_permlane32_swap((int)P2[1], (int)P2[3], false, false);
            auto s46 = __builtin_amdgcn_permlane32_swap((int)P2[4], (int)P2[6], false, false);
            auto s57 = __builtin_amdgcn_permlane32_swap((int)P2[5], (int)P2[7], false, false);
            v4i w0, w1;
            w0[0] = s02[0]; w0[1] = s13[0]; w0[2] = s02[1]; w0[3] = s13[1];
            w1[0] = s46[0]; w1[1] = s57[0]; w1[2] = s46[1]; w1[3] = s57[1];
            const bf16x8 pa0 = __builtin_bit_cast(bf16x8, w0);
            const bf16x8 pa1 = __builtin_bit_cast(bf16x8, w1);
#pragma unroll
            for (int ks = 0; ks < 2; ks++) {
                const bf16x8 pa = ks ? pa1 : pa0;
                const int cb = g * 32 + ks * 16 + hi * 8;
                bf16x8 vfa = *(const bf16x8*)&Vs[la * 64 + (cb ^ swl)];
                bf16x8 vfb = *(const bf16x8*)&Vs[(32 + la) * 64 + (cb ^ swl)];
                O0 = __builtin_amdgcn_mfma_f32_32x32x16_bf16(vfa, pa, O0, 0, 0, 0);
                O1 = __builtin_amdgcn_mfma_f32_32x32x16_bf16(vfb, pa, O1, 0, 0, 0);
            }
        }
    }
    l += __shfl_xor(l, 32, 64);
    const float inv = 1.f / l;
    u16* yrow = Yb + ((size_t)(b * T_) + q) * C_ + h * HD_;
#pragma unroll
    for (int r4 = 0; r4 < 4; r4++) {
        u32x2 st0, st1;
        st0[0] = pk2(O0[r4 * 4 + 0] * inv, O0[r4 * 4 + 1] * inv);
        st0[1] = pk2(O0[r4 * 4 + 2] * inv, O0[r4 * 4 + 3] * inv);
        st1[0] = pk2(O1[r4 * 4 + 0] * inv, O1[r4 * 4 + 1] * inv);
        st1[1] = pk2(O1[r4 * 4 + 2] * inv, O1[r4 * 4 + 3] * inv);
        *(u32x2*)(yrow + r4 * 8 + hi * 4)      = st0;
        *(u32x2*)(yrow + 32 + r4 * 8 + hi * 4) = st1;
    }
}

extern "C" void kernel_launch(void* const* d_in, const int* in_sizes, int n_in,
                              void* d_out, int out_size, void* d_ws, size_t ws_size,
                              hipStream_t stream) {
    const float* x      = (const float*)d_in[0];
    const float* w_attn = (const float*)d_in[1];
    const float* w_proj = (const float*)d_in[2];
    float* out = (float*)d_out;
    char* ws = (char*)d_ws;
    // lifetime-overlapped workspace, peak ~104.3 MB
    u16* Wpb = (u16*)(ws + 0);              // 2 MB,   live: all
    u16* Rp  = (u16*)(ws + 2097152);        // 256 KB, live: -> norm
    u16* Xb  = (u16*)(ws + 2359296);        // 16 MB,  live: -> gemm1
    u16* Wab = (u16*)(ws + 19136512);       // 6 MB,   live: -> gemm1
    u16* QKV = (u16*)(ws + 25427968);       // 48 MB,  live: gemm1 -> norm
    u16* Qn  = (u16*)(ws + 2359296);        // 16 MB,  over Xb (dead), norm -> attn
    u16* Kn  = (u16*)(ws + 75759616);       // 16 MB,  norm -> attn
    u16* Vt  = (u16*)(ws + 92536832);       // 16 MB,  norm -> attn  [bh][d][t]
    u16* Yb  = (u16*)(ws + 25427968);       // 16 MB,  over QKV (dead), attn -> gemm2

    cast_f32_bf16<<<8192, 256, 0, stream>>>(x, Xb, 2097152);
    cast_f32_bf16<<<3072, 256, 0, stream>>>(w_attn, Wab, 786432);
    cast_f32_bf16<<<1024, 256, 0, stream>>>(w_proj, Wpb, 262144);
    rope_tab<<<256, 256, 0, stream>>>(Rp);
    gemm_bt2<u16><<<dim3(24, 64), 256, 0, stream>>>(Xb, Wab, QKV, 8192, 3072, 1024);
    norm_rope<<<2048, 256, 0, stream>>>(QKV, Qn, Kn, Vt, Rp);
    attn_fwd5<<<1024, 256, 0, stream>>>(Qn, Kn, Vt, Yb);
    gemm_bt2<float><<<dim3(8, 64), 256, 0, stream>>>(Yb, Wpb, out, 8192, 1024, 1024);
}

// Round 9
// 249.794 us; speedup vs baseline: 1.5680x; 1.0972x over previous
//
#include <hip/hip_runtime.h>

typedef unsigned short u16;
typedef unsigned int u32;
typedef __attribute__((ext_vector_type(4))) int v4i;
typedef __attribute__((ext_vector_type(4))) float f32x4;
typedef __attribute__((ext_vector_type(16))) float f32x16;
typedef __attribute__((ext_vector_type(4))) u16 v4u;
typedef __attribute__((ext_vector_type(2))) u32 u32x2;
typedef __attribute__((ext_vector_type(8))) __bf16 bf16x8;

#define B_ 4
#define T_ 2048
#define C_ 1024
#define H_ 16
#define HD_ 64
#define C3_ 3072

__device__ __forceinline__ u16 f2b(float f) {
    unsigned u = __builtin_bit_cast(unsigned, f);
    u += 0x7FFFu + ((u >> 16) & 1u);
    return (u16)(u >> 16);
}
__device__ __forceinline__ float b2f(u16 h) {
    unsigned u = ((unsigned)h) << 16;
    return __builtin_bit_cast(float, u);
}
__device__ __forceinline__ u32 pk2(float lo, float hi) {
    __bf16 a = (__bf16)lo, b = (__bf16)hi;
    return (u32)__builtin_bit_cast(u16, a) | ((u32)__builtin_bit_cast(u16, b) << 16);
}
// async global->LDS, 16B per lane; LDS dest = uniform base + lane*16
__device__ __forceinline__ void glds16(const u16* g, u16* l) {
    __builtin_amdgcn_global_load_lds((const __attribute__((address_space(1))) void*)g,
                                     (__attribute__((address_space(3))) void*)l, 16, 0, 0);
}

// ---------------- cast f32 -> bf16 ----------------
__global__ __launch_bounds__(256) void cast_f32_bf16(const float* __restrict__ in,
                                                     u16* __restrict__ out, int n4) {
    int i = blockIdx.x * 256 + threadIdx.x;
    if (i >= n4) return;
    f32x4 v = *(const f32x4*)(in + (size_t)i * 4);
    v4u o;
    o[0] = f2b(v[0]); o[1] = f2b(v[1]); o[2] = f2b(v[2]); o[3] = f2b(v[3]);
    *(v4u*)(out + (size_t)i * 4) = o;
}

// ---------------- rope table ----------------
__global__ __launch_bounds__(256) void rope_tab(u16* __restrict__ rope) {
    int id = blockIdx.x * 256 + threadIdx.x;   // T_*32 entries
    int t = id >> 5, j = id & 31;
    float invf = exp2f(-(float)j * (13.287712379549449f / 32.0f));  // 10000^(-j/32)
    float fr = (float)t * invf;
    float s, c;
    sincosf(fr, &s, &c);
    rope[id * 2]     = f2b(c);
    rope[id * 2 + 1] = f2b(s);
}

// ---------------- GEMM v3: BK=64, global_load_lds, XOR-swizzled LDS ----------
// out[m][n] = sum_k A[m][k]*Bmat[n][k].  LDS [128][64] u16; slot' = slot ^ (row&7)
// (inverse-applied on the GLOBAL source; reads apply the same XOR).
__device__ __forceinline__ void store_out(u16* p, float v)   { *p = f2b(v); }
__device__ __forceinline__ void store_out(float* p, float v) { *p = v; }

template <typename OutT>
__global__ __launch_bounds__(256) void gemm_bt3(const u16* __restrict__ A, const u16* __restrict__ Bm,
                                                OutT* __restrict__ Cout, int Mdim, int Ndim, int Kdim) {
    __shared__ u16 As[8192];     // [128][64] swizzled, 16 KB
    __shared__ u16 Bs[8192];
    const int tid = threadIdx.x;
    const int row0 = blockIdx.y * 128;
    const int col0 = blockIdx.x * 128;
    const int w = tid >> 6, lane = tid & 63;
    const int wm = w >> 1, wn = w & 1;
    const int lr = lane & 15, lk = lane >> 4;

    const f32x4 zf = {0.f, 0.f, 0.f, 0.f};
    f32x4 acc[4][4];
#pragma unroll
    for (int m = 0; m < 4; m++)
#pragma unroll
        for (int n = 0; n < 4; n++) acc[m][n] = zf;

    const u16* Ab = A + (size_t)row0 * Kdim;
    const u16* Bb = Bm + (size_t)col0 * Kdim;
    // staging: 4 insts per matrix; inst j covers rows w*32+j*8 .. +8, 8 slots of 8 u16
    const int srw = lane >> 3;                       // 0..7 within inst
    const int gch = (lane & 7) ^ (srw & 7);          // inverse swizzle on global source
    const size_t grow[4] = {
        (size_t)(w * 32 + 0 * 8 + srw) * Kdim + gch * 8,
        (size_t)(w * 32 + 1 * 8 + srw) * Kdim + gch * 8,
        (size_t)(w * 32 + 2 * 8 + srw) * Kdim + gch * 8,
        (size_t)(w * 32 + 3 * 8 + srw) * Kdim + gch * 8 };
    // read-side: row&7 = lr&7 for all fragment rows; chunk' = (kk*4+lk) ^ (lr&7)
    const int rx = lr & 7;

    for (int k0 = 0; k0 < Kdim; k0 += 64) {
#pragma unroll
        for (int j = 0; j < 4; j++) glds16(Ab + grow[j] + k0, As + (w * 32 + j * 8) * 64);
#pragma unroll
        for (int j = 0; j < 4; j++) glds16(Bb + grow[j] + k0, Bs + (w * 32 + j * 8) * 64);
        __syncthreads();
#pragma unroll
        for (int kk = 0; kk < 2; kk++) {
            const int chx = ((kk * 4 + lk) ^ rx) * 8;
            bf16x8 af[4], bfr[4];
#pragma unroll
            for (int m = 0; m < 4; m++) af[m]  = *(const bf16x8*)&As[(wm * 64 + m * 16 + lr) * 64 + chx];
#pragma unroll
            for (int n = 0; n < 4; n++) bfr[n] = *(const bf16x8*)&Bs[(wn * 64 + n * 16 + lr) * 64 + chx];
#pragma unroll
            for (int m = 0; m < 4; m++)
#pragma unroll
                for (int n = 0; n < 4; n++)
                    acc[m][n] = __builtin_amdgcn_mfma_f32_16x16x32_bf16(af[m], bfr[n], acc[m][n], 0, 0, 0);
        }
        __syncthreads();
    }
#pragma unroll
    for (int m = 0; m < 4; m++)
#pragma unroll
        for (int n = 0; n < 4; n++) {
            const int rr = row0 + wm * 64 + m * 16 + lk * 4;
            const int cc = col0 + wn * 64 + n * 16 + lr;
#pragma unroll
            for (int j = 0; j < 4; j++)
                store_out(Cout + (size_t)(rr + j) * Ndim + cc, acc[m][n][j]);
        }
}

// ---------------- RMSNorm + RoPE for q,k; transpose v -> [bh][d][t] ----------
__global__ __launch_bounds__(256) void norm_rope(const u16* __restrict__ qkv, u16* __restrict__ Qn,
                                                 u16* __restrict__ Kn, u16* __restrict__ Vt,
                                                 const u16* __restrict__ rope) {
    __shared__ u16 sl[3][64][72];
    const int tid = threadIdx.x, bid = blockIdx.x;
    const int tt = bid & 31, bh = bid >> 5;
    const int b = bh >> 4, h = bh & 15;
    const int t0 = tt * 64;
    const size_t base = ((size_t)(b * T_) + t0) * C3_ + h * HD_;
#pragma unroll
    for (int i = 0; i < 6; i++) {
        int c = tid + i * 256;            // 1536 16B chunks
        int p = c >> 9, rc = c & 511;
        int r = rc >> 3, ch = rc & 7;
        *(v4i*)&sl[p][r][ch * 8] = *(const v4i*)(qkv + base + (size_t)r * C3_ + p * C_ + ch * 8);
    }
    __syncthreads();
    const int row = tid >> 2, q4 = tid & 3;  // 4 lanes per row
    const u16* rp = rope + (size_t)(t0 + row) * 64;
#pragma unroll
    for (int p = 0; p < 2; p++) {            // p=0: q, p=1: k
        float ss = 0.f;
#pragma unroll
        for (int j = 0; j < 16; j++) { float v = b2f(sl[p][row][q4 * 16 + j]); ss += v * v; }
        ss += __shfl_xor(ss, 1, 64);
        ss += __shfl_xor(ss, 2, 64);
        const float rms = rsqrtf(ss * (1.f / 64.f) + 1.1920929e-7f);
        u16* outp = (p == 0 ? Qn : Kn) + ((size_t)bh * T_ + t0 + row) * HD_;
#pragma unroll
        for (int j = 0; j < 16; j++) {
            int d = q4 * 16 + j;
            float y;
            if (d < 32) {
                float x1 = b2f(sl[p][row][d]) * rms;
                float x2 = b2f(sl[p][row][d + 32]) * rms;
                y = x1 * b2f(rp[d * 2]) + x2 * b2f(rp[d * 2 + 1]);      // x1*cos + x2*sin
            } else {
                int dd = d - 32;
                float x1 = b2f(sl[p][row][dd]) * rms;
                float x2 = b2f(sl[p][row][d]) * rms;
                y = x2 * b2f(rp[dd * 2]) - x1 * b2f(rp[dd * 2 + 1]);    // x2*cos - x1*sin
            }
            outp[d] = f2b(y);
        }
    }
    const int d = tid >> 2, tq = tid & 3;
    u16* vout = Vt + ((size_t)bh * HD_ + d) * T_ + t0 + tq * 16;
#pragma unroll
    for (int jj = 0; jj < 4; jj++) {
        v4u pk;
#pragma unroll
        for (int j2 = 0; j2 < 4; j2++) pk[j2] = sl[2][tq * 16 + jj * 4 + j2][d];
        *(v4u*)(vout + jj * 4) = pk;
    }
}

// ---------------- causal flash attention v6: permlane reduce + l-via-MFMA ----
__global__ __launch_bounds__(256, 4) void attn_fwd6(const u16* __restrict__ Qn, const u16* __restrict__ Kn,
                                                    const u16* __restrict__ Vt, u16* __restrict__ Yb) {
    __shared__ u16 Ks[64 * 64];
    __shared__ u16 Vs[64 * 64];
    const int tid = threadIdx.x;
    const int w = tid >> 6, lane = tid & 63, la = lane & 31, hi = lane >> 5;
    const int gid = blockIdx.x;
    const int bh = gid & 63, qb = 15 - (gid >> 6);
    const int b = bh >> 4, h = bh & 15;
    const int q0w = qb * 128 + w * 32;
    const int q = q0w + la;
    const u16* Qp = Qn + (size_t)bh * T_ * HD_;
    const u16* Kp = Kn + (size_t)bh * T_ * HD_;
    const u16* Vp = Vt + (size_t)bh * HD_ * T_;
    const float SC = 0.125f * 1.44269504088896341f;   // scale * log2(e)

    bf16x8 qf[4];
#pragma unroll
    for (int c = 0; c < 4; c++)
        qf[c] = *(const bf16x8*)(Qp + (size_t)q * HD_ + c * 16 + hi * 8);

    v4i oi; oi[0] = oi[1] = oi[2] = oi[3] = 0x3F803F80;        // bf16 1.0 x8
    const bf16x8 onesf = __builtin_bit_cast(bf16x8, oi);

    f32x16 O0, O1, lsum;
#pragma unroll
    for (int r = 0; r < 16; r++) { O0[r] = 0.f; O1[r] = 0.f; lsum[r] = 0.f; }
    float m = -3e38f;
    const int lastt = q0w >> 6;
    const int ntile = 2 * qb + 2;
    const int srow0 = tid >> 3, scol = (tid & 7) * 8;            // u16 units
    const int srow1 = srow0 + 32;
    const int sw0 = srow0 * 64 + (scol ^ ((srow0 & 7) << 3));
    const int sw1 = srow1 * 64 + (scol ^ ((srow1 & 7) << 3));
    const int swl = (la & 7) << 3;                               // frag-read XOR

    for (int kt = 0; kt < ntile; kt++) {
        const int kv0 = kt * 64;
        __syncthreads();
        *(v4i*)&Ks[sw0] = *(const v4i*)(Kp + (size_t)(kv0 + srow0) * HD_ + scol);
        *(v4i*)&Ks[sw1] = *(const v4i*)(Kp + (size_t)(kv0 + srow1) * HD_ + scol);
        *(v4i*)&Vs[sw0] = *(const v4i*)(Vp + (size_t)srow0 * T_ + kv0 + scol);
        *(v4i*)&Vs[sw1] = *(const v4i*)(Vp + (size_t)srow1 * T_ + kv0 + scol);
        __syncthreads();
        if (kv0 > q0w + 31) continue;      // past diagonal; barrier counts stay matched
        f32x16 s0, s1;
#pragma unroll
        for (int r = 0; r < 16; r++) { s0[r] = 0.f; s1[r] = 0.f; }
#pragma unroll
        for (int c = 0; c < 4; c++) {
            const int cb = c * 16 + hi * 8;
            bf16x8 kfa = *(const bf16x8*)&Ks[la * 64 + (cb ^ swl)];
            bf16x8 kfb = *(const bf16x8*)&Ks[(32 + la) * 64 + (cb ^ swl)];
            s0 = __builtin_amdgcn_mfma_f32_32x32x16_bf16(kfa, qf[c], s0, 0, 0, 0);
            s1 = __builtin_amdgcn_mfma_f32_32x32x16_bf16(kfb, qf[c], s1, 0, 0, 0);
        }
        if (kt == lastt) {
#pragma unroll
            for (int r = 0; r < 16; r++) {
                const int cr = (r & 3) + 8 * (r >> 2) + 4 * hi;
                if (kv0 + cr > q)      s0[r] = -3e38f;
                if (kv0 + 32 + cr > q) s1[r] = -3e38f;
            }
        }
        float mx = fmaxf(s0[0], s1[0]);
#pragma unroll
        for (int r = 1; r < 16; r++) mx = fmaxf(mx, fmaxf(s0[r], s1[r]));
        {   // cross-half max via permlane32_swap (VALU; replaces ds_bpermute)
            int mi = __builtin_bit_cast(int, mx);
            auto sw = __builtin_amdgcn_permlane32_swap(mi, mi, false, false);
            mx = fmaxf(__builtin_bit_cast(float, sw[0]), __builtin_bit_cast(float, sw[1]));
        }
        if (__ballot(mx > m + 16.6355324f)) {   // T13 defer-max (3.0/SC)
            const float mn = fmaxf(m, mx);
            const float al = exp2f((m - mn) * SC);
            m = mn;
            lsum[0] *= al;                      // only row 0 of lsum is consumed
            O0 *= al;
            O1 *= al;
        }
        const float nm = -m * SC;
        float p0[16], p1[16];
#pragma unroll
        for (int r = 0; r < 16; r++) {
            p0[r] = exp2f(fmaf(s0[r], SC, nm));
            p1[r] = exp2f(fmaf(s1[r], SC, nm));
        }
#pragma unroll
        for (int g = 0; g < 2; g++) {
            u32 P2[8];
#pragma unroll
            for (int j = 0; j < 8; j++)
                P2[j] = g ? pk2(p1[2 * j], p1[2 * j + 1]) : pk2(p0[2 * j], p0[2 * j + 1]);
            auto s02 = __builtin_amdgcn_permlane32_swap((int)P2[0], (int)P2[2], false, false);
            auto s13 = __builtin_amdgcn_permlane32_swap((int)P2[1], (int)P2[3], false, false);
            auto s46 = __builtin_amdgcn_permlane32_swap((int)P2[4], (int)P2[6], false, false);
            auto s57 = __builtin_amdgcn_permlane32_swap((int)P2[5], (int)P2[7], false, false);
            v4i w0, w1;
            w0[0] = s02[0]; w0[1] = s13[0]; w0[2] = s02[1]; w0[3] = s13[1];
            w1[0] = s46[0]; w1[1] = s57[0]; w1[2] = s46[1]; w1[3] = s57[1];
            const bf16x8 pa0 = __builtin_bit_cast(bf16x8, w0);
            const bf16x8 pa1 = __builtin_bit_cast(bf16x8, w1);
            // l via ones-row MFMA: C[r][q] += sum_k 1*P[k][q]  (full 64-key sum)
            lsum = __builtin_amdgcn_mfma_f32_32x32x16_bf16(onesf, pa0, lsum, 0, 0, 0);
            lsum = __builtin_amdgcn_mfma_f32_32x32x16_bf16(onesf, pa1, lsum, 0, 0, 0);
#pragma unroll
            for (int ks = 0; ks < 2; ks++) {
                const bf16x8 pa = ks ? pa1 : pa0;
                const int cb = g * 32 + ks * 16 + hi * 8;
                bf16x8 vfa = *(const bf16x8*)&Vs[la * 64 + (cb ^ swl)];
                bf16x8 vfb = *(const bf16x8*)&Vs[(32 + la) * 64 + (cb ^ swl)];
                O0 = __builtin_amdgcn_mfma_f32_32x32x16_bf16(vfa, pa, O0, 0, 0, 0);
                O1 = __builtin_amdgcn_mfma_f32_32x32x16_bf16(vfb, pa, O1, 0, 0, 0);
            }
        }
    }
    const float inv = 1.f / lsum[0];
    u16* yrow = Yb + ((size_t)(b * T_) + q) * C_ + h * HD_;
#pragma unroll
    for (int r4 = 0; r4 < 4; r4++) {
        u32x2 st0, st1;
        st0[0] = pk2(O0[r4 * 4 + 0] * inv, O0[r4 * 4 + 1] * inv);
        st0[1] = pk2(O0[r4 * 4 + 2] * inv, O0[r4 * 4 + 3] * inv);
        st1[0] = pk2(O1[r4 * 4 + 0] * inv, O1[r4 * 4 + 1] * inv);
        st1[1] = pk2(O1[r4 * 4 + 2] * inv, O1[r4 * 4 + 3] * inv);
        *(u32x2*)(yrow + r4 * 8 + hi * 4)      = st0;
        *(u32x2*)(yrow + 32 + r4 * 8 + hi * 4) = st1;
    }
}

extern "C" void kernel_launch(void* const* d_in, const int* in_sizes, int n_in,
                              void* d_out, int out_size, void* d_ws, size_t ws_size,
                              hipStream_t stream) {
    const float* x      = (const float*)d_in[0];
    const float* w_attn = (const float*)d_in[1];
    const float* w_proj = (const float*)d_in[2];
    float* out = (float*)d_out;
    char* ws = (char*)d_ws;
    // lifetime-overlapped workspace, peak ~104.3 MB
    u16* Wpb = (u16*)(ws + 0);              // 2 MB,   live: all
    u16* Rp  = (u16*)(ws + 2097152);        // 256 KB, live: -> norm
    u16* Xb  = (u16*)(ws + 2359296);        // 16 MB,  live: -> gemm1
    u16* Wab = (u16*)(ws + 19136512);       // 6 MB,   live: -> gemm1
    u16* QKV = (u16*)(ws + 25427968);       // 48 MB,  live: gemm1 -> norm
    u16* Qn  = (u16*)(ws + 2359296);        // 16 MB,  over Xb (dead), norm -> attn
    u16* Kn  = (u16*)(ws + 75759616);       // 16 MB,  norm -> attn
    u16* Vt  = (u16*)(ws + 92536832);       // 16 MB,  norm -> attn  [bh][d][t]
    u16* Yb  = (u16*)(ws + 25427968);       // 16 MB,  over QKV (dead), attn -> gemm2

    cast_f32_bf16<<<8192, 256, 0, stream>>>(x, Xb, 2097152);
    cast_f32_bf16<<<3072, 256, 0, stream>>>(w_attn, Wab, 786432);
    cast_f32_bf16<<<1024, 256, 0, stream>>>(w_proj, Wpb, 262144);
    rope_tab<<<256, 256, 0, stream>>>(Rp);
    gemm_bt3<u16><<<dim3(24, 64), 256, 0, stream>>>(Xb, Wab, QKV, 8192, 3072, 1024);
    norm_rope<<<2048, 256, 0, stream>>>(QKV, Qn, Kn, Vt, Rp);
    attn_fwd6<<<1024, 256, 0, stream>>>(Qn, Kn, Vt, Yb);
    gemm_bt3<float><<<dim3(8, 64), 256, 0, stream>>>(Yb, Wpb, out, 8192, 1024, 1024);
}